// Round 5
// baseline (2505.031 us; speedup 1.0000x reference)
//
#include <hip/hip_runtime.h>
#include <stdint.h>

#define NTOK 1536
#define CDIM 768
#define NH 8
#define DKH 64
#define DVH 96
#define NF 96

typedef unsigned short u16;

__device__ __forceinline__ float b2f(u16 u) {
    union { uint32_t i; float f; } v; v.i = ((uint32_t)u) << 16; return v.f;
}
// dtype-branched load: f32 flag selects fp32 vs bf16 decode
__device__ __forceinline__ float ldin(const void* p, int i, int f32) {
    return f32 ? ((const float*)p)[i] : b2f(((const u16*)p)[i]);
}

// ---------------------------------------------------------------------------
// ws layout (float offsets).  flags[0..8] at ws[0..8].  Total ~15.8 MB.
// ---------------------------------------------------------------------------
#define OFF_WSUF 16
#define OFF_QB   (OFF_WSUF + 11 * 512)        // 5648
#define OFF_KB   (OFF_QB + NH * NTOK * DKH)   // +786432
#define OFF_VB   (OFF_KB + NH * NTOK * DKH)   // +786432
#define OFF_AO   (OFF_VB + NH * NTOK * DVH)   // +1179648
// end = OFF_AO + NTOK*CDIM = 3,937,808 floats = 15.8 MB

struct In9 { const void* p[9]; int n[9]; };

// ---------------------------------------------------------------------------
// Kernel P: per-input dtype probe. flags[k]=1 iff input k is fp32.
// ---------------------------------------------------------------------------
__global__ __launch_bounds__(256) void probe_all(In9 s, int* __restrict__ flags) {
    __shared__ int bad;
    int k = blockIdx.x;
    if (threadIdx.x == 0) bad = 0;
    __syncthreads();
    const u16* a = (const u16*)s.p[k];
    int n = s.n[k];
    int my = 0;
    for (int i = threadIdx.x; i < n; i += 256) {
        float v = b2f(a[i]);
        if (!(fabsf(v) < 1e6f)) my = 1;  // inf/nan/huge
    }
    if (my) atomicOr(&bad, 1);
    __syncthreads();
    if (threadIdx.x == 0) flags[k] = bad;
}

// ---------------------------------------------------------------------------
// Kernel 0: wsuf[t][hd] = sum_{f>=t} Wpos[f][hd], t<11.
// posk[j,hd] == wsuf[31-clz(|j-(n-1)|+1)][hd]  (proven collapse of
// central_mask_embed @ Wpos; cross-validated vs literal posk in R3).
// ---------------------------------------------------------------------------
__global__ __launch_bounds__(512) void wsuf_k(const void* __restrict__ Wpos,
                                              int fi, float* __restrict__ ws) {
    int f32 = ((const int*)ws)[fi];
    int hd = threadIdx.x;  // 0..511
    float s = 0.f;
    for (int f = NF - 1; f >= 0; --f) {
        s += ldin(Wpos, f * 512 + hd, f32);
        if (f < 11) ws[OFF_WSUF + f * 512 + hd] = s;
    }
}

// ---------------------------------------------------------------------------
// Kernel 1: brute-force QKV projection. One thread per output element.
// q stored scaled by 1/8.  Layouts: q,k (h,i,d64); v (h,i,d96).
// ---------------------------------------------------------------------------
__global__ __launch_bounds__(256) void qkv_brute(const void* __restrict__ x,
                                                 const void* __restrict__ Wq,
                                                 const void* __restrict__ Wk,
                                                 const void* __restrict__ Wv,
                                                 int fx, int fq, int fk, int fv,
                                                 float* __restrict__ ws) {
    const int* flags = (const int*)ws;
    int gid = blockIdx.x * 256 + threadIdx.x;  // 1536*1792 exact
    int c = gid % 1792;
    int i = gid / 1792;

    const void* W; int ldb, cc, fw;
    if (c < 512)       { W = Wq; ldb = 512;  cc = c;        fw = flags[fq]; }
    else if (c < 1024) { W = Wk; ldb = 512;  cc = c - 512;  fw = flags[fk]; }
    else               { W = Wv; ldb = CDIM; cc = c - 1024; fw = flags[fv]; }
    int f32x = flags[fx];

    float acc = 0.f;
    for (int k = 0; k < CDIM; ++k)
        acc += ldin(x, i * CDIM + k, f32x) * ldin(W, k * ldb + cc, fw);

    if (c < 512) {
        int h = c >> 6, d = c & 63;
        ws[OFF_QB + (h * NTOK + i) * DKH + d] = acc * 0.125f;  // 1/sqrt(64)
    } else if (c < 1024) {
        int c2 = c - 512;
        int h = c2 >> 6, d = c2 & 63;
        ws[OFF_KB + (h * NTOK + i) * DKH + d] = acc;
    } else {
        int c2 = c - 1024;
        int h = c2 / 96, d = c2 % 96;
        ws[OFF_VB + (h * NTOK + i) * DVH + d] = acc;
    }
}

// ---------------------------------------------------------------------------
// Kernel 2: brute-force attention, one block per (h, i) row.
// logits_j = (q+rcb).k_j + t11[log2floor(|i-j|+1)]; softmax; @ V.
// ---------------------------------------------------------------------------
__global__ __launch_bounds__(256) void attn_brute(const void* __restrict__ rcb,
                                                  const void* __restrict__ rpb,
                                                  int fc, int fp,
                                                  float* __restrict__ ws) {
    __shared__ float qc[DKH], qp[DKH], t11[16];
    __shared__ float sc[NTOK];
    __shared__ float red[256];
    const int* flags = (const int*)ws;
    const float* qb = ws + OFF_QB;
    const float* kb = ws + OFF_KB;
    const float* vb = ws + OFF_VB;
    float* ao       = ws + OFF_AO;

    int h = blockIdx.x & 7;
    int i = blockIdx.x >> 3;  // grid 12288 = 1536*8
    int tid = threadIdx.x;

    if (tid < DKH) {
        float q = qb[(h * NTOK + i) * DKH + tid];
        qc[tid] = q + ldin(rcb, h * DKH + tid, flags[fc]);
        qp[tid] = q + ldin(rpb, h * DKH + tid, flags[fp]);
    }
    __syncthreads();
    if (tid < 11) {
        const float* wp = ws + OFF_WSUF + tid * 512 + h * DKH;
        float sdot = 0.f;
        for (int d = 0; d < DKH; ++d) sdot += qp[d] * wp[d];
        t11[tid] = sdot;
    }
    __syncthreads();

    float lmax = -1e30f;
    for (int j = tid; j < NTOK; j += 256) {
        const float* krow = &kb[(h * NTOK + j) * DKH];
        float s = 0.f;
        for (int d = 0; d < DKH; ++d) s += qc[d] * krow[d];
        int dd = i - j; dd = dd < 0 ? -dd : dd;
        s += t11[31 - __builtin_clz(dd + 1)];
        sc[j] = s;
        lmax = fmaxf(lmax, s);
    }
    red[tid] = lmax;
    __syncthreads();
    for (int st = 128; st > 0; st >>= 1) {
        if (tid < st) red[tid] = fmaxf(red[tid], red[tid + st]);
        __syncthreads();
    }
    float m = red[0];
    __syncthreads();

    float lsum = 0.f;
    for (int j = tid; j < NTOK; j += 256) {
        float p = __expf(sc[j] - m);
        sc[j] = p;
        lsum += p;
    }
    red[tid] = lsum;
    __syncthreads();
    for (int st = 128; st > 0; st >>= 1) {
        if (tid < st) red[tid] += red[tid + st];
        __syncthreads();
    }
    float inv = 1.f / red[0];

    for (int d = tid; d < DVH; d += 256) {
        float acc = 0.f;
        for (int j = 0; j < NTOK; ++j) acc += sc[j] * vb[(h * NTOK + j) * DVH + d];
        ao[i * CDIM + h * DVH + d] = acc * inv;
    }
}

// ---------------------------------------------------------------------------
// Kernel 3: brute-force output projection + bias -> FP32 (the fix: d_out is
// the reference's output dtype = float32, not bf16).
// ---------------------------------------------------------------------------
__global__ __launch_bounds__(256) void out_brute(const void* __restrict__ Wout,
                                                 const void* __restrict__ bout,
                                                 int fw, int fb,
                                                 const float* __restrict__ ws,
                                                 float* __restrict__ out) {
    const int* flags = (const int*)ws;
    const float* ao = ws + OFF_AO;
    int gid = blockIdx.x * 256 + threadIdx.x;  // 1536*768 exact
    int c = gid % CDIM;
    int i = gid / CDIM;
    float acc = ldin(bout, c, flags[fb]);
    for (int k = 0; k < CDIM; ++k)
        acc += ao[i * CDIM + k] * ldin(Wout, k * CDIM + c, flags[fw]);
    out[i * CDIM + c] = acc;
}

// ---------------------------------------------------------------------------
extern "C" void kernel_launch(void* const* d_in, const int* in_sizes, int n_in,
                              void* d_out, int out_size, void* d_ws, size_t ws_size,
                              hipStream_t stream) {
    float* out = (float*)d_out;
    float* ws = (float*)d_ws;

    // Role resolution by flat size (≡ positional under documented dict order;
    // robust to permutations up to within-same-size-pair order).
    const int want[9] = {1179648, 393216, 393216, 589824, 589824, 768, 49152, 512, 512};
    int role2in[9], used[9] = {0};
    bool ok = (n_in == 9);
    if (ok) {
        for (int r = 0; r < 9; ++r) {
            int found = -1;
            for (int i = 0; i < 9 && found < 0; ++i)
                if (!used[i] && in_sizes[i] == want[r]) found = i;
            if (found < 0) { ok = false; break; }
            used[found] = 1;
            role2in[r] = found;
        }
    }
    if (!ok) for (int r = 0; r < 9; ++r) role2in[r] = r;

    const void* x    = d_in[role2in[0]];
    const void* Wq   = d_in[role2in[1]];
    const void* Wk   = d_in[role2in[2]];
    const void* Wv   = d_in[role2in[3]];
    const void* Wout = d_in[role2in[4]];
    const void* bout = d_in[role2in[5]];
    const void* Wpos = d_in[role2in[6]];
    const void* rcb  = d_in[role2in[7]];
    const void* rpb  = d_in[role2in[8]];

    In9 s;
    for (int i = 0; i < 9; ++i) { s.p[i] = d_in[i]; s.n[i] = in_sizes[i]; }
    hipLaunchKernelGGL(probe_all, dim3(9), dim3(256), 0, stream, s, (int*)ws);

    hipLaunchKernelGGL(wsuf_k, dim3(1), dim3(512), 0, stream,
                       Wpos, role2in[6], ws);
    hipLaunchKernelGGL(qkv_brute, dim3((NTOK * 1792) / 256), dim3(256), 0, stream,
                       x, Wq, Wk, Wv, role2in[0], role2in[1], role2in[2], role2in[3], ws);
    hipLaunchKernelGGL(attn_brute, dim3(NTOK * NH), dim3(256), 0, stream,
                       rcb, rpb, role2in[7], role2in[8], ws);
    hipLaunchKernelGGL(out_brute, dim3((NTOK * CDIM) / 256), dim3(256), 0, stream,
                       Wout, bout, role2in[4], role2in[5], ws, out);
}

// Round 6
// 443.257 us; speedup vs baseline: 5.6514x; 5.6514x over previous
//
#include <hip/hip_runtime.h>
#include <stdint.h>

#define NTOK 1536
#define CDIM 768
#define NH 8
#define DKH 64
#define DVH 96
#define NF 96

typedef unsigned short u16;

__device__ __forceinline__ float b2f(u16 u) {
    union { uint32_t i; float f; } v; v.i = ((uint32_t)u) << 16; return v.f;
}
__device__ __forceinline__ float ldin(const void* p, int i, int f32) {
    return f32 ? ((const float*)p)[i] : b2f(((const u16*)p)[i]);
}
__device__ __forceinline__ float f4get(float4 v, int t) {
    switch (t) { case 0: return v.x; case 1: return v.y; case 2: return v.z; default: return v.w; }
}

// ---------------------------------------------------------------------------
// ws layout (float offsets). flags[0..8] at ws[0..8]. Total ~16.3 MB
// (R2 ran a 29 MB layout uncorrupted -> ws_size is ample).
// ---------------------------------------------------------------------------
#define OFF_WSUF 16
#define OFF_QB   (OFF_WSUF + 11 * 512)
#define OFF_KB   (OFF_QB + NH * NTOK * DKH)
#define OFF_VB   (OFF_KB + NH * NTOK * DKH)
#define OFF_S11  (OFF_VB + NH * NTOK * DVH)
#define OFF_AO   (OFF_S11 + NH * NTOK * 12)

struct In9 { const void* p[9]; int n[9]; };

// ---------------------------------------------------------------------------
// Kernel P: per-input dtype probe (capped scan). flags[k]=1 iff fp32.
// ---------------------------------------------------------------------------
__global__ __launch_bounds__(256) void probe_all(In9 s, int* __restrict__ flags) {
    __shared__ int bad;
    int k = blockIdx.x;
    if (threadIdx.x == 0) bad = 0;
    __syncthreads();
    const u16* a = (const u16*)s.p[k];
    int n = s.n[k];
    if (n > 65536) n = 65536;
    int my = 0;
    for (int i = threadIdx.x; i < n; i += 256) {
        float v = b2f(a[i]);
        if (!(fabsf(v) < 1e6f)) my = 1;
    }
    if (my) atomicOr(&bad, 1);
    __syncthreads();
    if (threadIdx.x == 0) flags[k] = bad;
}

// ---------------------------------------------------------------------------
// Kernel 0: wsuf[t][hd] = sum_{f>=t} Wpos[f][hd], t<11 (validated collapse).
// ---------------------------------------------------------------------------
__global__ __launch_bounds__(512) void wsuf_k(const void* __restrict__ Wpos,
                                              int fi, float* __restrict__ ws) {
    int f32 = ((const int*)ws)[fi];
    int hd = threadIdx.x;
    float s = 0.f;
    for (int f = NF - 1; f >= 0; --f) {
        s += ldin(Wpos, f * 512 + hd, f32);
        if (f < 11) ws[OFF_WSUF + f * 512 + hd] = s;
    }
}

// ---------------------------------------------------------------------------
// Kernel 1: tiled QKV GEMM (validated in R2; dtype-branched staging).
// ---------------------------------------------------------------------------
__global__ __launch_bounds__(256) void qkv_gemm(const void* __restrict__ x,
                                                const void* __restrict__ Wq,
                                                const void* __restrict__ Wk,
                                                const void* __restrict__ Wv,
                                                int fx, int fq, int fk, int fv,
                                                float* __restrict__ ws) {
    __shared__ float As[64][17];
    __shared__ float Bs[16][64];
    const int* flags = (const int*)ws;
    float* qb = ws + OFF_QB;
    float* kb = ws + OFF_KB;
    float* vb = ws + OFF_VB;

    int tx = threadIdx.x, ty = threadIdx.y;
    int tid = ty * 16 + tx;
    int i0 = blockIdx.x * 64;
    int n0 = blockIdx.y * 64;

    const void* Bmat; int ldb, col0, fB;
    if (n0 < 512)       { Bmat = Wq; ldb = 512;  col0 = n0;        fB = flags[fq]; }
    else if (n0 < 1024) { Bmat = Wk; ldb = 512;  col0 = n0 - 512;  fB = flags[fk]; }
    else                { Bmat = Wv; ldb = CDIM; col0 = n0 - 1024; fB = flags[fv]; }
    int f32x = flags[fx];

    int arow = tid >> 2;
    int akk  = (tid & 3) * 4;
    int bkk  = tid >> 4;
    int bcol = (tid & 15) * 4;

    float acc[4][4];
#pragma unroll
    for (int a = 0; a < 4; ++a)
#pragma unroll
        for (int b = 0; b < 4; ++b) acc[a][b] = 0.f;

    for (int k0 = 0; k0 < CDIM; k0 += 16) {
        if (f32x) {
            float4 av = *(const float4*)((const float*)x + (i0 + arow) * CDIM + k0 + akk);
            As[arow][akk + 0] = av.x; As[arow][akk + 1] = av.y;
            As[arow][akk + 2] = av.z; As[arow][akk + 3] = av.w;
        } else {
            ushort4 av = *(const ushort4*)((const u16*)x + (i0 + arow) * CDIM + k0 + akk);
            As[arow][akk + 0] = b2f(av.x); As[arow][akk + 1] = b2f(av.y);
            As[arow][akk + 2] = b2f(av.z); As[arow][akk + 3] = b2f(av.w);
        }
        if (fB) {
            float4 bv = *(const float4*)((const float*)Bmat + (k0 + bkk) * ldb + col0 + bcol);
            Bs[bkk][bcol + 0] = bv.x; Bs[bkk][bcol + 1] = bv.y;
            Bs[bkk][bcol + 2] = bv.z; Bs[bkk][bcol + 3] = bv.w;
        } else {
            ushort4 bv = *(const ushort4*)((const u16*)Bmat + (k0 + bkk) * ldb + col0 + bcol);
            Bs[bkk][bcol + 0] = b2f(bv.x); Bs[bkk][bcol + 1] = b2f(bv.y);
            Bs[bkk][bcol + 2] = b2f(bv.z); Bs[bkk][bcol + 3] = b2f(bv.w);
        }
        __syncthreads();
#pragma unroll
        for (int kk = 0; kk < 16; ++kk) {
            float4 b4 = *(const float4*)&Bs[kk][tx * 4];
            float a4[4];
#pragma unroll
            for (int a = 0; a < 4; ++a) a4[a] = As[ty * 4 + a][kk];
#pragma unroll
            for (int a = 0; a < 4; ++a) {
                acc[a][0] = fmaf(a4[a], b4.x, acc[a][0]);
                acc[a][1] = fmaf(a4[a], b4.y, acc[a][1]);
                acc[a][2] = fmaf(a4[a], b4.z, acc[a][2]);
                acc[a][3] = fmaf(a4[a], b4.w, acc[a][3]);
            }
        }
        __syncthreads();
    }

#pragma unroll
    for (int a = 0; a < 4; ++a) {
        int i = i0 + ty * 4 + a;
#pragma unroll
        for (int b = 0; b < 4; ++b) {
            int c = n0 + tx * 4 + b;
            float val = acc[a][b];
            if (c < 512) {
                int h = c >> 6, d = c & 63;
                qb[(h * NTOK + i) * DKH + d] = val * 0.125f;
            } else if (c < 1024) {
                int cc = c - 512;
                int h = cc >> 6, d = cc & 63;
                kb[(h * NTOK + i) * DKH + d] = val;
            } else {
                int cc = c - 1024;
                int h = cc / 96, d = cc % 96;
                vb[(h * NTOK + i) * DVH + d] = val;
            }
        }
    }
}

// ---------------------------------------------------------------------------
// Kernel 2: S11[h,i,t] = (q_scaled + rpb) . wsuf[t]  (validated in R2).
// ---------------------------------------------------------------------------
__global__ __launch_bounds__(256) void s11_kernel(int fp, float* __restrict__ ws,
                                                  const void* __restrict__ rpb) {
    __shared__ float qs[32][68];
    const int* flags = (const int*)ws;
    const float* qb = ws + OFF_QB;
    const float* wsuf = ws + OFF_WSUF;
    float* s11 = ws + OFF_S11;
    int f32 = flags[fp];
    int tid = threadIdx.x;
    int h = blockIdx.x & 7;
    int i0 = (blockIdx.x >> 3) * 32;
    for (int idx = tid; idx < 32 * 64; idx += 256) {
        int r = idx >> 6, d = idx & 63;
        qs[r][d] = qb[(h * NTOK + i0 + r) * DKH + d] + ldin(rpb, h * 64 + d, f32);
    }
    __syncthreads();
    for (int idx = tid; idx < 32 * 12; idx += 256) {
        int r = idx / 12, t = idx % 12;
        float s = 0.f;
        if (t < 11) {
            const float* wp = wsuf + t * 512 + h * 64;
            for (int d = 0; d < 64; ++d) s += qs[r][d] * wp[d];
        }
        s11[(h * NTOK + i0 + r) * 12 + t] = s;
    }
}

// ---------------------------------------------------------------------------
// Kernel 3: flash attention (validated in R2). BR=48, BC=64, 256 blocks.
// ---------------------------------------------------------------------------
__global__ __launch_bounds__(256) void attn_kernel(int fc, float* __restrict__ ws,
                                                   const void* __restrict__ rcb) {
    __shared__ float qcs[48][68];
    __shared__ float kvbuf[64 * 100];
    __shared__ float ps[48][68];
    __shared__ float s11s[48][12];
    __shared__ float red[48][16];
    __shared__ float mrow[48], lrow[48], arow[48];

    const int* flags = (const int*)ws;
    const float* qb = ws + OFF_QB;
    const float* kb = ws + OFF_KB;
    const float* vb = ws + OFF_VB;
    const float* s11 = ws + OFF_S11;
    float* ao = ws + OFF_AO;
    int f32c = flags[fc];

    int tx = threadIdx.x, ty = threadIdx.y;
    int tid = ty * 16 + tx;
    int h = blockIdx.x & 7;
    int i0 = (blockIdx.x >> 3) * 48;
    int r0 = ty * 3;

    for (int idx = tid; idx < 48 * 64; idx += 256) {
        int r = idx >> 6, d = idx & 63;
        qcs[r][d] = qb[(h * NTOK + i0 + r) * DKH + d] + ldin(rcb, h * 64 + d, f32c);
    }
    for (int idx = tid; idx < 48 * 12; idx += 256) {
        int r = idx / 12, t = idx % 12;
        s11s[r][t] = s11[(h * NTOK + i0 + r) * 12 + t];
    }
    if (tid < 48) { mrow[tid] = -1e30f; lrow[tid] = 0.f; }

    float o[3][6];
#pragma unroll
    for (int a = 0; a < 3; ++a)
#pragma unroll
        for (int b = 0; b < 6; ++b) o[a][b] = 0.f;

    for (int jb = 0; jb < NTOK / 64; ++jb) {
        int j0 = jb * 64;
#pragma unroll
        for (int u = 0; u < 4; ++u) {
            int q4 = tid * 4 + u;
            int j = q4 >> 4;
            int d0 = (q4 & 15) * 4;
            float4 kv = *(const float4*)&kb[(h * NTOK + j0 + j) * DKH + d0];
            kvbuf[(d0 + 0) * 68 + j] = kv.x;
            kvbuf[(d0 + 1) * 68 + j] = kv.y;
            kvbuf[(d0 + 2) * 68 + j] = kv.z;
            kvbuf[(d0 + 3) * 68 + j] = kv.w;
        }
        __syncthreads();  // b1

        float s[3][4];
#pragma unroll
        for (int a = 0; a < 3; ++a)
#pragma unroll
            for (int b = 0; b < 4; ++b) s[a][b] = 0.f;

        for (int d4 = 0; d4 < 64; d4 += 4) {
            float4 qrow[3];
#pragma unroll
            for (int a = 0; a < 3; ++a) qrow[a] = *(const float4*)&qcs[r0 + a][d4];
#pragma unroll
            for (int t = 0; t < 4; ++t) {
                float4 kv = *(const float4*)&kvbuf[(d4 + t) * 68 + tx * 4];
#pragma unroll
                for (int a = 0; a < 3; ++a) {
                    float qv = f4get(qrow[a], t);
                    s[a][0] = fmaf(qv, kv.x, s[a][0]);
                    s[a][1] = fmaf(qv, kv.y, s[a][1]);
                    s[a][2] = fmaf(qv, kv.z, s[a][2]);
                    s[a][3] = fmaf(qv, kv.w, s[a][3]);
                }
            }
        }
#pragma unroll
        for (int a = 0; a < 3; ++a) {
            int ig = i0 + r0 + a;
#pragma unroll
            for (int b = 0; b < 4; ++b) {
                int jg = j0 + tx * 4 + b;
                int dd = ig - jg; dd = dd < 0 ? -dd : dd;
                s[a][b] += s11s[r0 + a][31 - __builtin_clz(dd + 1)];
            }
        }
#pragma unroll
        for (int a = 0; a < 3; ++a)
            red[r0 + a][tx] = fmaxf(fmaxf(s[a][0], s[a][1]), fmaxf(s[a][2], s[a][3]));
        __syncthreads();  // b2
        if (tid < 48) {
            float m = red[tid][0];
#pragma unroll
            for (int t = 1; t < 16; ++t) m = fmaxf(m, red[tid][t]);
            float mo = mrow[tid];
            float mn = fmaxf(mo, m);
            float al = __expf(mo - mn);
            mrow[tid] = mn; arow[tid] = al; lrow[tid] *= al;
        }
        __syncthreads();  // b3
#pragma unroll
        for (int u = 0; u < 6; ++u) {
            int q4 = tid * 6 + u;
            int j = q4 / 24;
            int d0 = (q4 % 24) * 4;
            float4 vv = *(const float4*)&vb[(h * NTOK + j0 + j) * DVH + d0];
            *(float4*)&kvbuf[j * 100 + d0] = vv;
        }
#pragma unroll
        for (int a = 0; a < 3; ++a) {
            float m = mrow[r0 + a];
            float rs = 0.f;
#pragma unroll
            for (int b = 0; b < 4; ++b) {
                float p = __expf(s[a][b] - m);
                ps[r0 + a][tx * 4 + b] = p;
                rs += p;
            }
            red[r0 + a][tx] = rs;
        }
        __syncthreads();  // b4
        if (tid < 48) {
            float ssum = 0.f;
#pragma unroll
            for (int t = 0; t < 16; ++t) ssum += red[tid][t];
            lrow[tid] += ssum;
        }
        float al[3] = { arow[r0], arow[r0 + 1], arow[r0 + 2] };
#pragma unroll
        for (int a = 0; a < 3; ++a)
#pragma unroll
            for (int b = 0; b < 6; ++b) o[a][b] *= al[a];

        for (int j4 = 0; j4 < 64; j4 += 4) {
            float4 prow[3];
#pragma unroll
            for (int a = 0; a < 3; ++a) prow[a] = *(const float4*)&ps[r0 + a][j4];
#pragma unroll
            for (int t = 0; t < 4; ++t) {
                const float* vrow = &kvbuf[(j4 + t) * 100 + tx * 6];
                float v0 = vrow[0], v1 = vrow[1], v2 = vrow[2];
                float v3 = vrow[3], v4 = vrow[4], v5 = vrow[5];
#pragma unroll
                for (int a = 0; a < 3; ++a) {
                    float pv = f4get(prow[a], t);
                    o[a][0] = fmaf(pv, v0, o[a][0]);
                    o[a][1] = fmaf(pv, v1, o[a][1]);
                    o[a][2] = fmaf(pv, v2, o[a][2]);
                    o[a][3] = fmaf(pv, v3, o[a][3]);
                    o[a][4] = fmaf(pv, v4, o[a][4]);
                    o[a][5] = fmaf(pv, v5, o[a][5]);
                }
            }
        }
        __syncthreads();  // b5
    }

#pragma unroll
    for (int a = 0; a < 3; ++a) {
        int r = r0 + a;
        float inv = 1.f / lrow[r];
        int ig = i0 + r;
#pragma unroll
        for (int b = 0; b < 6; ++b)
            ao[ig * CDIM + h * DVH + tx * 6 + b] = o[a][b] * inv;
    }
}

// ---------------------------------------------------------------------------
// Kernel 4: output GEMM + bias -> FP32 out (validated structure, fixed dtype).
// ---------------------------------------------------------------------------
__global__ __launch_bounds__(256) void out_gemm(const void* __restrict__ Wout,
                                                const void* __restrict__ bout,
                                                int fw, int fb,
                                                float* __restrict__ ws,
                                                float* __restrict__ out) {
    __shared__ float As[64][17];
    __shared__ float Bs[16][64];
    const int* flags = (const int*)ws;
    const float* A = ws + OFF_AO;
    int f32w = flags[fw], f32b = flags[fb];

    int tx = threadIdx.x, ty = threadIdx.y;
    int tid = ty * 16 + tx;
    int i0 = blockIdx.x * 64;
    int n0 = blockIdx.y * 64;

    int arow = tid >> 2;
    int akk  = (tid & 3) * 4;
    int bkk  = tid >> 4;
    int bcol = (tid & 15) * 4;

    float acc[4][4];
#pragma unroll
    for (int a = 0; a < 4; ++a)
#pragma unroll
        for (int b = 0; b < 4; ++b) acc[a][b] = 0.f;

    for (int k0 = 0; k0 < CDIM; k0 += 16) {
        float4 av = *(const float4*)&A[(i0 + arow) * CDIM + k0 + akk];
        As[arow][akk + 0] = av.x; As[arow][akk + 1] = av.y;
        As[arow][akk + 2] = av.z; As[arow][akk + 3] = av.w;
        if (f32w) {
            float4 bv = *(const float4*)((const float*)Wout + (k0 + bkk) * CDIM + n0 + bcol);
            Bs[bkk][bcol + 0] = bv.x; Bs[bkk][bcol + 1] = bv.y;
            Bs[bkk][bcol + 2] = bv.z; Bs[bkk][bcol + 3] = bv.w;
        } else {
            ushort4 bv = *(const ushort4*)((const u16*)Wout + (k0 + bkk) * CDIM + n0 + bcol);
            Bs[bkk][bcol + 0] = b2f(bv.x); Bs[bkk][bcol + 1] = b2f(bv.y);
            Bs[bkk][bcol + 2] = b2f(bv.z); Bs[bkk][bcol + 3] = b2f(bv.w);
        }
        __syncthreads();
#pragma unroll
        for (int kk = 0; kk < 16; ++kk) {
            float4 b4 = *(const float4*)&Bs[kk][tx * 4];
            float a4[4];
#pragma unroll
            for (int a = 0; a < 4; ++a) a4[a] = As[ty * 4 + a][kk];
#pragma unroll
            for (int a = 0; a < 4; ++a) {
                acc[a][0] = fmaf(a4[a], b4.x, acc[a][0]);
                acc[a][1] = fmaf(a4[a], b4.y, acc[a][1]);
                acc[a][2] = fmaf(a4[a], b4.z, acc[a][2]);
                acc[a][3] = fmaf(a4[a], b4.w, acc[a][3]);
            }
        }
        __syncthreads();
    }

#pragma unroll
    for (int a = 0; a < 4; ++a) {
        int i = i0 + ty * 4 + a;
        int c = n0 + tx * 4;
        float4 ov;
        ov.x = acc[a][0] + ldin(bout, c + 0, f32b);
        ov.y = acc[a][1] + ldin(bout, c + 1, f32b);
        ov.z = acc[a][2] + ldin(bout, c + 2, f32b);
        ov.w = acc[a][3] + ldin(bout, c + 3, f32b);
        *(float4*)&out[i * CDIM + c] = ov;
    }
}

// ---------------------------------------------------------------------------
extern "C" void kernel_launch(void* const* d_in, const int* in_sizes, int n_in,
                              void* d_out, int out_size, void* d_ws, size_t ws_size,
                              hipStream_t stream) {
    float* out = (float*)d_out;
    float* ws = (float*)d_ws;

    const int want[9] = {1179648, 393216, 393216, 589824, 589824, 768, 49152, 512, 512};
    int role2in[9], used[9] = {0};
    bool ok = (n_in == 9);
    if (ok) {
        for (int r = 0; r < 9; ++r) {
            int found = -1;
            for (int i = 0; i < 9 && found < 0; ++i)
                if (!used[i] && in_sizes[i] == want[r]) found = i;
            if (found < 0) { ok = false; break; }
            used[found] = 1;
            role2in[r] = found;
        }
    }
    if (!ok) for (int r = 0; r < 9; ++r) role2in[r] = r;

    const void* x    = d_in[role2in[0]];
    const void* Wq   = d_in[role2in[1]];
    const void* Wk   = d_in[role2in[2]];
    const void* Wv   = d_in[role2in[3]];
    const void* Wout = d_in[role2in[4]];
    const void* bout = d_in[role2in[5]];
    const void* Wpos = d_in[role2in[6]];
    const void* rcb  = d_in[role2in[7]];
    const void* rpb  = d_in[role2in[8]];

    In9 s;
    for (int i = 0; i < 9; ++i) { s.p[i] = d_in[i]; s.n[i] = in_sizes[i]; }
    hipLaunchKernelGGL(probe_all, dim3(9), dim3(256), 0, stream, s, (int*)ws);

    hipLaunchKernelGGL(wsuf_k, dim3(1), dim3(512), 0, stream, Wpos, role2in[6], ws);
    hipLaunchKernelGGL(qkv_gemm, dim3(24, 28), dim3(16, 16), 0, stream,
                       x, Wq, Wk, Wv, role2in[0], role2in[1], role2in[2], role2in[3], ws);
    hipLaunchKernelGGL(s11_kernel, dim3(384), dim3(256), 0, stream,
                       role2in[8], ws, rpb);
    hipLaunchKernelGGL(attn_kernel, dim3(256), dim3(16, 16), 0, stream,
                       role2in[7], ws, rcb);
    hipLaunchKernelGGL(out_gemm, dim3(24, 12), dim3(16, 16), 0, stream,
                       Wout, bout, role2in[4], role2in[5], ws, out);
}

// Round 7
// 398.059 us; speedup vs baseline: 6.2931x; 1.1135x over previous
//
#include <hip/hip_runtime.h>
#include <stdint.h>

#define NTOK 1536
#define CDIM 768
#define NH 8
#define DKH 64
#define DVH 96
#define NF 96

typedef unsigned short u16;
typedef __attribute__((ext_vector_type(8))) short s16x8;   // 8 bf16 (4 VGPRs)
typedef __attribute__((ext_vector_type(4))) float f32x4;   // MFMA acc

__device__ __forceinline__ float b2f(u16 u) {
    union { uint32_t i; float f; } v; v.i = ((uint32_t)u) << 16; return v.f;
}
__device__ __forceinline__ u16 f2b(float f) {
    union { float f; uint32_t i; } v; v.f = f;
    uint32_t x = v.i;
    return (u16)((x + 0x7FFFu + ((x >> 16) & 1u)) >> 16);
}
__device__ __forceinline__ float ldin(const void* p, int i, int f32) {
    return f32 ? ((const float*)p)[i] : b2f(((const u16*)p)[i]);
}
__device__ __forceinline__ float f4get(float4 v, int t) {
    switch (t) { case 0: return v.x; case 1: return v.y; case 2: return v.z; default: return v.w; }
}

// ---------------------------------------------------------------------------
// ws layout (float offsets). flags[0..8] at ws[0..8]. ~16.3 MB.
// ---------------------------------------------------------------------------
#define OFF_WSUF 16
#define OFF_QB   (OFF_WSUF + 11 * 512)
#define OFF_KB   (OFF_QB + NH * NTOK * DKH)
#define OFF_VB   (OFF_KB + NH * NTOK * DKH)
#define OFF_S11  (OFF_VB + NH * NTOK * DVH)
#define OFF_AO   (OFF_S11 + NH * NTOK * 12)

struct In9 { const void* p[9]; int n[9]; };

// ---------------------------------------------------------------------------
// Kernel P: per-input dtype probe (capped scan). flags[k]=1 iff fp32.
// ---------------------------------------------------------------------------
__global__ __launch_bounds__(256) void probe_all(In9 s, int* __restrict__ flags) {
    __shared__ int bad;
    int k = blockIdx.x;
    if (threadIdx.x == 0) bad = 0;
    __syncthreads();
    const u16* a = (const u16*)s.p[k];
    int n = s.n[k];
    if (n > 65536) n = 65536;
    int my = 0;
    for (int i = threadIdx.x; i < n; i += 256) {
        float v = b2f(a[i]);
        if (!(fabsf(v) < 1e6f)) my = 1;
    }
    if (my) atomicOr(&bad, 1);
    __syncthreads();
    if (threadIdx.x == 0) flags[k] = bad;
}

// ---------------------------------------------------------------------------
// Kernel 0: wsuf[t][hd] = sum_{f>=t} Wpos[f][hd], t<11 (validated collapse).
// ---------------------------------------------------------------------------
__global__ __launch_bounds__(512) void wsuf_k(const void* __restrict__ Wpos,
                                              int fi, float* __restrict__ ws) {
    int f32 = ((const int*)ws)[fi];
    int hd = threadIdx.x;
    float s = 0.f;
    for (int f = NF - 1; f >= 0; --f) {
        s += ldin(Wpos, f * 512 + hd, f32);
        if (f < 11) ws[OFF_WSUF + f * 512 + hd] = s;
    }
}

// ---------------------------------------------------------------------------
// Kernel 1: QKV GEMM via bf16 MFMA 16x16x32.  Block: 256 thr (4 waves),
// tile 64(M)x64(N), BK=64.  A,B^T staged in LDS bf16 (stride 72 -> b128
// reads 2-way conflict = free).  Fragment maps per m89/m91 verification.
// ---------------------------------------------------------------------------
__global__ __launch_bounds__(256) void qkv_mfma(const void* __restrict__ x,
                                                const void* __restrict__ Wq,
                                                const void* __restrict__ Wk,
                                                const void* __restrict__ Wv,
                                                int fx, int fq, int fk, int fv,
                                                float* __restrict__ ws) {
    __shared__ alignas(16) u16 As[64 * 72];
    __shared__ alignas(16) u16 Bs[64 * 72];
    const int* flags = (const int*)ws;
    float* qb = ws + OFF_QB;
    float* kb = ws + OFF_KB;
    float* vb = ws + OFF_VB;

    int tid = threadIdx.x;
    int lane = tid & 63, w = tid >> 6;
    int quad = lane >> 4, col = lane & 15;
    int i0 = blockIdx.x * 64;
    int n0 = blockIdx.y * 64;

    const void* Bmat; int ldb, col0, fB;
    if (n0 < 512)       { Bmat = Wq; ldb = 512;  col0 = n0;        fB = flags[fq]; }
    else if (n0 < 1024) { Bmat = Wk; ldb = 512;  col0 = n0 - 512;  fB = flags[fk]; }
    else                { Bmat = Wv; ldb = CDIM; col0 = n0 - 1024; fB = flags[fv]; }
    int f32x = flags[fx];

    f32x4 acc[4];
#pragma unroll
    for (int mt = 0; mt < 4; ++mt) acc[mt] = (f32x4){0.f, 0.f, 0.f, 0.f};

    for (int k0 = 0; k0 < CDIM; k0 += 64) {
        // stage A (64 rows x 64 k) as bf16, row-major stride 72
#pragma unroll
        for (int u = 0; u < 4; ++u) {
            int s = tid * 4 + u;
            int row = s >> 4, c4 = (s & 15) * 4;
            ushort4 o;
            if (f32x) {
                float4 v = *(const float4*)((const float*)x + (i0 + row) * CDIM + k0 + c4);
                o.x = f2b(v.x); o.y = f2b(v.y); o.z = f2b(v.z); o.w = f2b(v.w);
            } else {
                o = *(const ushort4*)((const u16*)x + (i0 + row) * CDIM + k0 + c4);
            }
            *(ushort4*)&As[row * 72 + c4] = o;
        }
        // stage B^T (64 n-rows x 64 k) as bf16
#pragma unroll
        for (int u = 0; u < 4; ++u) {
            int s = tid * 4 + u;
            int krow = s >> 4, c4 = (s & 15) * 4;
            u16 b0, b1, b2, b3;
            if (fB) {
                float4 v = *(const float4*)((const float*)Bmat + (k0 + krow) * ldb + col0 + c4);
                b0 = f2b(v.x); b1 = f2b(v.y); b2 = f2b(v.z); b3 = f2b(v.w);
            } else {
                ushort4 v = *(const ushort4*)((const u16*)Bmat + (k0 + krow) * ldb + col0 + c4);
                b0 = v.x; b1 = v.y; b2 = v.z; b3 = v.w;
            }
            Bs[(c4 + 0) * 72 + krow] = b0;
            Bs[(c4 + 1) * 72 + krow] = b1;
            Bs[(c4 + 2) * 72 + krow] = b2;
            Bs[(c4 + 3) * 72 + krow] = b3;
        }
        __syncthreads();
#pragma unroll
        for (int kc = 0; kc < 2; ++kc) {
            s16x8 bfrag = *(const s16x8*)&Bs[(w * 16 + col) * 72 + kc * 32 + quad * 8];
#pragma unroll
            for (int mt = 0; mt < 4; ++mt) {
                s16x8 afrag = *(const s16x8*)&As[(mt * 16 + col) * 72 + kc * 32 + quad * 8];
                acc[mt] = __builtin_amdgcn_mfma_f32_16x16x32_bf16(afrag, bfrag, acc[mt], 0, 0, 0);
            }
        }
        __syncthreads();
    }

    // epilogue: D[row=quad*4+r][col=lane&15]
    int c = n0 + w * 16 + col;
#pragma unroll
    for (int mt = 0; mt < 4; ++mt) {
#pragma unroll
        for (int r = 0; r < 4; ++r) {
            int i = i0 + mt * 16 + quad * 4 + r;
            float val = acc[mt][r];
            if (c < 512) {
                int h = c >> 6, d = c & 63;
                qb[(h * NTOK + i) * DKH + d] = val * 0.125f;
            } else if (c < 1024) {
                int cc = c - 512;
                int h = cc >> 6, d = cc & 63;
                kb[(h * NTOK + i) * DKH + d] = val;
            } else {
                int cc = c - 1024;
                int h = cc / 96, d = cc % 96;
                vb[(h * NTOK + i) * DVH + d] = val;
            }
        }
    }
}

// ---------------------------------------------------------------------------
// Kernel 2: S11[h,i,t] = (q_scaled + rpb) . wsuf[t]  (validated).
// ---------------------------------------------------------------------------
__global__ __launch_bounds__(256) void s11_kernel(int fp, float* __restrict__ ws,
                                                  const void* __restrict__ rpb) {
    __shared__ float qs[32][68];
    const int* flags = (const int*)ws;
    const float* qb = ws + OFF_QB;
    const float* wsuf = ws + OFF_WSUF;
    float* s11 = ws + OFF_S11;
    int f32 = flags[fp];
    int tid = threadIdx.x;
    int h = blockIdx.x & 7;
    int i0 = (blockIdx.x >> 3) * 32;
    for (int idx = tid; idx < 32 * 64; idx += 256) {
        int r = idx >> 6, d = idx & 63;
        qs[r][d] = qb[(h * NTOK + i0 + r) * DKH + d] + ldin(rpb, h * 64 + d, f32);
    }
    __syncthreads();
    for (int idx = tid; idx < 32 * 12; idx += 256) {
        int r = idx / 12, t = idx % 12;
        float s = 0.f;
        if (t < 11) {
            const float* wp = wsuf + t * 512 + h * 64;
            for (int d = 0; d < 64; ++d) s += qs[r][d] * wp[d];
        }
        s11[(h * NTOK + i0 + r) * 12 + t] = s;
    }
}

// ---------------------------------------------------------------------------
// Kernel 3: flash attention.  BR=24 rows/block, 128 threads, grid 512
// (2 blocks/CU -> barrier overlap).  Same validated barrier structure.
// ---------------------------------------------------------------------------
__global__ __launch_bounds__(128) void attn_kernel(int fc, float* __restrict__ ws,
                                                   const void* __restrict__ rcb) {
    __shared__ float qcs[24][68];
    __shared__ float kvbuf[64 * 100];  // K^T [d*68+j] then V [j*100+c]
    __shared__ float ps[24][68];
    __shared__ float s11s[24][12];
    __shared__ float red[24][16];
    __shared__ float mrow[24], lrow[24], arow[24];

    const int* flags = (const int*)ws;
    const float* qb = ws + OFF_QB;
    const float* kb = ws + OFF_KB;
    const float* vb = ws + OFF_VB;
    const float* s11 = ws + OFF_S11;
    float* ao = ws + OFF_AO;
    int f32c = flags[fc];

    int tx = threadIdx.x, ty = threadIdx.y;   // 16 x 8
    int tid = ty * 16 + tx;
    int h = blockIdx.x & 7;
    int i0 = (blockIdx.x >> 3) * 24;
    int r0 = ty * 3;

    for (int idx = tid; idx < 24 * 64; idx += 128) {
        int r = idx >> 6, d = idx & 63;
        qcs[r][d] = qb[(h * NTOK + i0 + r) * DKH + d] + ldin(rcb, h * 64 + d, f32c);
    }
    for (int idx = tid; idx < 24 * 12; idx += 128) {
        int r = idx / 12, t = idx % 12;
        s11s[r][t] = s11[(h * NTOK + i0 + r) * 12 + t];
    }
    if (tid < 24) { mrow[tid] = -1e30f; lrow[tid] = 0.f; }

    float o[3][6];
#pragma unroll
    for (int a = 0; a < 3; ++a)
#pragma unroll
        for (int b = 0; b < 6; ++b) o[a][b] = 0.f;

    for (int jb = 0; jb < NTOK / 64; ++jb) {
        int j0 = jb * 64;
        // ---- load K^T ----
#pragma unroll
        for (int u = 0; u < 8; ++u) {
            int q4 = tid * 8 + u;
            int j = q4 >> 4;
            int d0 = (q4 & 15) * 4;
            float4 kv = *(const float4*)&kb[(h * NTOK + j0 + j) * DKH + d0];
            kvbuf[(d0 + 0) * 68 + j] = kv.x;
            kvbuf[(d0 + 1) * 68 + j] = kv.y;
            kvbuf[(d0 + 2) * 68 + j] = kv.z;
            kvbuf[(d0 + 3) * 68 + j] = kv.w;
        }
        __syncthreads();  // b1

        float s[3][4];
#pragma unroll
        for (int a = 0; a < 3; ++a)
#pragma unroll
            for (int b = 0; b < 4; ++b) s[a][b] = 0.f;

        for (int d4 = 0; d4 < 64; d4 += 4) {
            float4 qrow[3];
#pragma unroll
            for (int a = 0; a < 3; ++a) qrow[a] = *(const float4*)&qcs[r0 + a][d4];
#pragma unroll
            for (int t = 0; t < 4; ++t) {
                float4 kv = *(const float4*)&kvbuf[(d4 + t) * 68 + tx * 4];
#pragma unroll
                for (int a = 0; a < 3; ++a) {
                    float qv = f4get(qrow[a], t);
                    s[a][0] = fmaf(qv, kv.x, s[a][0]);
                    s[a][1] = fmaf(qv, kv.y, s[a][1]);
                    s[a][2] = fmaf(qv, kv.z, s[a][2]);
                    s[a][3] = fmaf(qv, kv.w, s[a][3]);
                }
            }
        }
#pragma unroll
        for (int a = 0; a < 3; ++a) {
            int ig = i0 + r0 + a;
#pragma unroll
            for (int b = 0; b < 4; ++b) {
                int jg = j0 + tx * 4 + b;
                int dd = ig - jg; dd = dd < 0 ? -dd : dd;
                s[a][b] += s11s[r0 + a][31 - __builtin_clz(dd + 1)];
            }
        }
#pragma unroll
        for (int a = 0; a < 3; ++a)
            red[r0 + a][tx] = fmaxf(fmaxf(s[a][0], s[a][1]), fmaxf(s[a][2], s[a][3]));
        __syncthreads();  // b2
        if (tid < 24) {
            float m = red[tid][0];
#pragma unroll
            for (int t = 1; t < 16; ++t) m = fmaxf(m, red[tid][t]);
            float mo = mrow[tid];
            float mn = fmaxf(mo, m);
            float al = __expf(mo - mn);
            mrow[tid] = mn; arow[tid] = al; lrow[tid] *= al;
        }
        __syncthreads();  // b3
        // ---- load V (K reads done before b2) ----
#pragma unroll
        for (int u = 0; u < 12; ++u) {
            int q4 = tid * 12 + u;
            int j = q4 / 24;
            int d0 = (q4 % 24) * 4;
            float4 vv = *(const float4*)&vb[(h * NTOK + j0 + j) * DVH + d0];
            *(float4*)&kvbuf[j * 100 + d0] = vv;
        }
#pragma unroll
        for (int a = 0; a < 3; ++a) {
            float m = mrow[r0 + a];
            float rs = 0.f;
#pragma unroll
            for (int b = 0; b < 4; ++b) {
                float p = __expf(s[a][b] - m);
                ps[r0 + a][tx * 4 + b] = p;
                rs += p;
            }
            red[r0 + a][tx] = rs;
        }
        __syncthreads();  // b4
        if (tid < 24) {
            float ssum = 0.f;
#pragma unroll
            for (int t = 0; t < 16; ++t) ssum += red[tid][t];
            lrow[tid] += ssum;
        }
        float al[3] = { arow[r0], arow[r0 + 1], arow[r0 + 2] };
#pragma unroll
        for (int a = 0; a < 3; ++a)
#pragma unroll
            for (int b = 0; b < 6; ++b) o[a][b] *= al[a];

        for (int j4 = 0; j4 < 64; j4 += 4) {
            float4 prow[3];
#pragma unroll
            for (int a = 0; a < 3; ++a) prow[a] = *(const float4*)&ps[r0 + a][j4];
#pragma unroll
            for (int t = 0; t < 4; ++t) {
                const float* vrow = &kvbuf[(j4 + t) * 100 + tx * 6];
                float v0 = vrow[0], v1 = vrow[1], v2 = vrow[2];
                float v3 = vrow[3], v4 = vrow[4], v5 = vrow[5];
#pragma unroll
                for (int a = 0; a < 3; ++a) {
                    float pv = f4get(prow[a], t);
                    o[a][0] = fmaf(pv, v0, o[a][0]);
                    o[a][1] = fmaf(pv, v1, o[a][1]);
                    o[a][2] = fmaf(pv, v2, o[a][2]);
                    o[a][3] = fmaf(pv, v3, o[a][3]);
                    o[a][4] = fmaf(pv, v4, o[a][4]);
                    o[a][5] = fmaf(pv, v5, o[a][5]);
                }
            }
        }
        __syncthreads();  // b5
    }

#pragma unroll
    for (int a = 0; a < 3; ++a) {
        int r = r0 + a;
        float inv = 1.f / lrow[r];
        int ig = i0 + r;
#pragma unroll
        for (int b = 0; b < 6; ++b)
            ao[ig * CDIM + h * DVH + tx * 6 + b] = o[a][b] * inv;
    }
}

// ---------------------------------------------------------------------------
// Kernel 4: output GEMM via bf16 MFMA + bias -> fp32 out.
// ---------------------------------------------------------------------------
__global__ __launch_bounds__(256) void out_mfma(const void* __restrict__ Wout,
                                                const void* __restrict__ bout,
                                                int fw, int fb,
                                                float* __restrict__ ws,
                                                float* __restrict__ out) {
    __shared__ alignas(16) u16 As[64 * 72];
    __shared__ alignas(16) u16 Bs[64 * 72];
    const int* flags = (const int*)ws;
    const float* A = ws + OFF_AO;
    int f32w = flags[fw], f32b = flags[fb];

    int tid = threadIdx.x;
    int lane = tid & 63, w = tid >> 6;
    int quad = lane >> 4, col = lane & 15;
    int i0 = blockIdx.x * 64;
    int n0 = blockIdx.y * 64;

    f32x4 acc[4];
#pragma unroll
    for (int mt = 0; mt < 4; ++mt) acc[mt] = (f32x4){0.f, 0.f, 0.f, 0.f};

    for (int k0 = 0; k0 < CDIM; k0 += 64) {
#pragma unroll
        for (int u = 0; u < 4; ++u) {
            int s = tid * 4 + u;
            int row = s >> 4, c4 = (s & 15) * 4;
            float4 v = *(const float4*)&A[(i0 + row) * CDIM + k0 + c4];
            ushort4 o;
            o.x = f2b(v.x); o.y = f2b(v.y); o.z = f2b(v.z); o.w = f2b(v.w);
            *(ushort4*)&As[row * 72 + c4] = o;
        }
#pragma unroll
        for (int u = 0; u < 4; ++u) {
            int s = tid * 4 + u;
            int krow = s >> 4, c4 = (s & 15) * 4;
            u16 b0, b1, b2, b3;
            if (f32w) {
                float4 v = *(const float4*)((const float*)Wout + (k0 + krow) * CDIM + n0 + c4);
                b0 = f2b(v.x); b1 = f2b(v.y); b2 = f2b(v.z); b3 = f2b(v.w);
            } else {
                ushort4 v = *(const ushort4*)((const u16*)Wout + (k0 + krow) * CDIM + n0 + c4);
                b0 = v.x; b1 = v.y; b2 = v.z; b3 = v.w;
            }
            Bs[(c4 + 0) * 72 + krow] = b0;
            Bs[(c4 + 1) * 72 + krow] = b1;
            Bs[(c4 + 2) * 72 + krow] = b2;
            Bs[(c4 + 3) * 72 + krow] = b3;
        }
        __syncthreads();
#pragma unroll
        for (int kc = 0; kc < 2; ++kc) {
            s16x8 bfrag = *(const s16x8*)&Bs[(w * 16 + col) * 72 + kc * 32 + quad * 8];
#pragma unroll
            for (int mt = 0; mt < 4; ++mt) {
                s16x8 afrag = *(const s16x8*)&As[(mt * 16 + col) * 72 + kc * 32 + quad * 8];
                acc[mt] = __builtin_amdgcn_mfma_f32_16x16x32_bf16(afrag, bfrag, acc[mt], 0, 0, 0);
            }
        }
        __syncthreads();
    }

    int c = n0 + w * 16 + col;
    float bias = ldin(bout, c, f32b);
#pragma unroll
    for (int mt = 0; mt < 4; ++mt) {
#pragma unroll
        for (int r = 0; r < 4; ++r) {
            int i = i0 + mt * 16 + quad * 4 + r;
            out[i * CDIM + c] = acc[mt][r] + bias;
        }
    }
}

// ---------------------------------------------------------------------------
extern "C" void kernel_launch(void* const* d_in, const int* in_sizes, int n_in,
                              void* d_out, int out_size, void* d_ws, size_t ws_size,
                              hipStream_t stream) {
    float* out = (float*)d_out;
    float* ws = (float*)d_ws;

    const int want[9] = {1179648, 393216, 393216, 589824, 589824, 768, 49152, 512, 512};
    int role2in[9], used[9] = {0};
    bool ok = (n_in == 9);
    if (ok) {
        for (int r = 0; r < 9; ++r) {
            int found = -1;
            for (int i = 0; i < 9 && found < 0; ++i)
                if (!used[i] && in_sizes[i] == want[r]) found = i;
            if (found < 0) { ok = false; break; }
            used[found] = 1;
            role2in[r] = found;
        }
    }
    if (!ok) for (int r = 0; r < 9; ++r) role2in[r] = r;

    const void* x    = d_in[role2in[0]];
    const void* Wq   = d_in[role2in[1]];
    const void* Wk   = d_in[role2in[2]];
    const void* Wv   = d_in[role2in[3]];
    const void* Wout = d_in[role2in[4]];
    const void* bout = d_in[role2in[5]];
    const void* Wpos = d_in[role2in[6]];
    const void* rcb  = d_in[role2in[7]];
    const void* rpb  = d_in[role2in[8]];

    In9 s;
    for (int i = 0; i < 9; ++i) { s.p[i] = d_in[i]; s.n[i] = in_sizes[i]; }
    hipLaunchKernelGGL(probe_all, dim3(9), dim3(256), 0, stream, s, (int*)ws);

    hipLaunchKernelGGL(wsuf_k, dim3(1), dim3(512), 0, stream, Wpos, role2in[6], ws);
    hipLaunchKernelGGL(qkv_mfma, dim3(24, 28), dim3(256), 0, stream,
                       x, Wq, Wk, Wv, role2in[0], role2in[1], role2in[2], role2in[3], ws);
    hipLaunchKernelGGL(s11_kernel, dim3(384), dim3(256), 0, stream,
                       role2in[8], ws, rpb);
    hipLaunchKernelGGL(attn_kernel, dim3(512), dim3(16, 8), 0, stream,
                       role2in[7], ws, rcb);
    hipLaunchKernelGGL(out_mfma, dim3(24, 12), dim3(256), 0, stream,
                       Wout, bout, role2in[4], role2in[5], ws, out);
}

// Round 8
// 238.243 us; speedup vs baseline: 10.5146x; 1.6708x over previous
//
#include <hip/hip_runtime.h>
#include <stdint.h>

#define NTOK 1536
#define CDIM 768
#define NH 8
#define DKH 64
#define DVH 96
#define NF 96

typedef unsigned short u16;
typedef __attribute__((ext_vector_type(8))) short s16x8;   // 8 bf16 (4 VGPRs)
typedef __attribute__((ext_vector_type(4))) float f32x4;   // MFMA acc

__device__ __forceinline__ float b2f(u16 u) {
    union { uint32_t i; float f; } v; v.i = ((uint32_t)u) << 16; return v.f;
}
__device__ __forceinline__ u16 f2b(float f) {
    union { float f; uint32_t i; } v; v.f = f;
    uint32_t x = v.i;
    return (u16)((x + 0x7FFFu + ((x >> 16) & 1u)) >> 16);
}
__device__ __forceinline__ float ldin(const void* p, int i, int f32) {
    return f32 ? ((const float*)p)[i] : b2f(((const u16*)p)[i]);
}

// ---------------------------------------------------------------------------
// ws layout (float offsets). flags[0..8] at ws[0..8]. ~11.6 MB total.
// ---------------------------------------------------------------------------
#define OFF_WSUF 16
#define OFF_S11  (OFF_WSUF + 5632)
#define OFF_QB   (OFF_S11 + 147456)
#define OFF_QC16 (OFF_QB + 786432)     // u16[786432]: bf16 (q*0.125 + rcb), (h,i,d)
#define OFF_KB16 (OFF_QC16 + 393216)   // u16[786432]: bf16 k, (h,j,d)
#define OFF_VT16 (OFF_KB16 + 393216)   // u16[1179648]: bf16 v transposed, (h,d,j)
#define OFF_AOB  (OFF_VT16 + 589824)   // u16[1179648]: bf16 attention out, (i, h*96+d)

struct In9 { const void* p[9]; int n[9]; };

// ---------------------------------------------------------------------------
// Kernel P: per-input dtype probe (2048-elem scan; fp32 misread as bf16 hits
// |v|>1e6 w.p. ~0.4/word -> certain; true bf16 never does).
// ---------------------------------------------------------------------------
__global__ __launch_bounds__(256) void probe_all(In9 s, int* __restrict__ flags) {
    __shared__ int bad;
    int k = blockIdx.x;
    if (threadIdx.x == 0) bad = 0;
    __syncthreads();
    const u16* a = (const u16*)s.p[k];
    int n = s.n[k];
    if (n > 2048) n = 2048;
    int my = 0;
    for (int i = threadIdx.x; i < n; i += 256) {
        float v = b2f(a[i]);
        if (!(fabsf(v) < 1e6f)) my = 1;
    }
    if (my) atomicOr(&bad, 1);
    __syncthreads();
    if (threadIdx.x == 0) flags[k] = bad;
}

// ---------------------------------------------------------------------------
// Kernel 0: wsuf[t][hd] = sum_{f>=t} Wpos[f][hd], t<11.  Parallel: block=t.
// ---------------------------------------------------------------------------
__global__ __launch_bounds__(512) void wsuf_k(const void* __restrict__ Wpos,
                                              int fi, float* __restrict__ ws) {
    int f32 = ((const int*)ws)[fi];
    int hd = threadIdx.x;
    int t = blockIdx.x;  // 0..10
    float s = 0.f;
    for (int f = t; f < NF; ++f) s += ldin(Wpos, f * 512 + hd, f32);
    ws[OFF_WSUF + t * 512 + hd] = s;
}

// ---------------------------------------------------------------------------
// Kernel 1: QKV GEMM via bf16 MFMA 16x16x32 (validated R7 structure).
// Epilogue: q -> fp32 qb (scaled); k -> bf16 kb16 (h,j,d); v -> bf16 vt16 (h,d,j).
// ---------------------------------------------------------------------------
__global__ __launch_bounds__(256) void qkv_mfma(const void* __restrict__ x,
                                                const void* __restrict__ Wq,
                                                const void* __restrict__ Wk,
                                                const void* __restrict__ Wv,
                                                int fx, int fq, int fk, int fv,
                                                float* __restrict__ ws) {
    __shared__ alignas(16) u16 As[64 * 72];
    __shared__ alignas(16) u16 Bs[64 * 72];
    const int* flags = (const int*)ws;
    float* qb = ws + OFF_QB;
    u16* kb16 = (u16*)(ws + OFF_KB16);
    u16* vt16 = (u16*)(ws + OFF_VT16);

    int tid = threadIdx.x;
    int lane = tid & 63, w = tid >> 6;
    int quad = lane >> 4, col = lane & 15;
    int i0 = blockIdx.x * 64;
    int n0 = blockIdx.y * 64;

    const void* Bmat; int ldb, col0, fB;
    if (n0 < 512)       { Bmat = Wq; ldb = 512;  col0 = n0;        fB = flags[fq]; }
    else if (n0 < 1024) { Bmat = Wk; ldb = 512;  col0 = n0 - 512;  fB = flags[fk]; }
    else                { Bmat = Wv; ldb = CDIM; col0 = n0 - 1024; fB = flags[fv]; }
    int f32x = flags[fx];

    f32x4 acc[4];
#pragma unroll
    for (int mt = 0; mt < 4; ++mt) acc[mt] = (f32x4){0.f, 0.f, 0.f, 0.f};

    for (int k0 = 0; k0 < CDIM; k0 += 64) {
#pragma unroll
        for (int u = 0; u < 4; ++u) {
            int s = tid * 4 + u;
            int row = s >> 4, c4 = (s & 15) * 4;
            ushort4 o;
            if (f32x) {
                float4 v = *(const float4*)((const float*)x + (i0 + row) * CDIM + k0 + c4);
                o.x = f2b(v.x); o.y = f2b(v.y); o.z = f2b(v.z); o.w = f2b(v.w);
            } else {
                o = *(const ushort4*)((const u16*)x + (i0 + row) * CDIM + k0 + c4);
            }
            *(ushort4*)&As[row * 72 + c4] = o;
        }
#pragma unroll
        for (int u = 0; u < 4; ++u) {
            int s = tid * 4 + u;
            int krow = s >> 4, c4 = (s & 15) * 4;
            u16 b0, b1, b2, b3;
            if (fB) {
                float4 v = *(const float4*)((const float*)Bmat + (k0 + krow) * ldb + col0 + c4);
                b0 = f2b(v.x); b1 = f2b(v.y); b2 = f2b(v.z); b3 = f2b(v.w);
            } else {
                ushort4 v = *(const ushort4*)((const u16*)Bmat + (k0 + krow) * ldb + col0 + c4);
                b0 = v.x; b1 = v.y; b2 = v.z; b3 = v.w;
            }
            Bs[(c4 + 0) * 72 + krow] = b0;
            Bs[(c4 + 1) * 72 + krow] = b1;
            Bs[(c4 + 2) * 72 + krow] = b2;
            Bs[(c4 + 3) * 72 + krow] = b3;
        }
        __syncthreads();
#pragma unroll
        for (int kc = 0; kc < 2; ++kc) {
            s16x8 bfrag = *(const s16x8*)&Bs[(w * 16 + col) * 72 + kc * 32 + quad * 8];
#pragma unroll
            for (int mt = 0; mt < 4; ++mt) {
                s16x8 afrag = *(const s16x8*)&As[(mt * 16 + col) * 72 + kc * 32 + quad * 8];
                acc[mt] = __builtin_amdgcn_mfma_f32_16x16x32_bf16(afrag, bfrag, acc[mt], 0, 0, 0);
            }
        }
        __syncthreads();
    }

    int c = n0 + w * 16 + col;
#pragma unroll
    for (int mt = 0; mt < 4; ++mt) {
#pragma unroll
        for (int r = 0; r < 4; ++r) {
            int i = i0 + mt * 16 + quad * 4 + r;
            float val = acc[mt][r];
            if (c < 512) {
                int h = c >> 6, d = c & 63;
                qb[(h * NTOK + i) * DKH + d] = val * 0.125f;
            } else if (c < 1024) {
                int cc = c - 512;
                int h = cc >> 6, d = cc & 63;
                kb16[(h * NTOK + i) * DKH + d] = f2b(val);
            } else {
                int cc = c - 1024;
                int h = cc / 96, d = cc % 96;
                vt16[(h * DVH + d) * NTOK + i] = f2b(val);
            }
        }
    }
}

// ---------------------------------------------------------------------------
// Kernel 2: s11[h,i,t] = qb[h,i].wsuf[t] + rpb[h].wsuf[t]; also emits
// qc16[h,i,d] = bf16(qb + rcb).
// ---------------------------------------------------------------------------
__global__ __launch_bounds__(256) void s11_kernel(int fp, int fc,
                                                  float* __restrict__ ws,
                                                  const void* __restrict__ rpb,
                                                  const void* __restrict__ rcb) {
    __shared__ float qs[32][68];
    __shared__ float rpd[12];
    const int* flags = (const int*)ws;
    const float* qb = ws + OFF_QB;
    const float* wsuf = ws + OFF_WSUF;
    float* s11 = ws + OFF_S11;
    u16* qc16 = (u16*)(ws + OFF_QC16);
    int f32p = flags[fp], f32c = flags[fc];
    int tid = threadIdx.x;
    int h = blockIdx.x & 7;
    int i0 = (blockIdx.x >> 3) * 32;

    for (int idx = tid; idx < 32 * 64; idx += 256) {
        int r = idx >> 6, d = idx & 63;
        qs[r][d] = qb[(h * NTOK + i0 + r) * DKH + d];
    }
    if (tid < 12) {
        float s = 0.f;
        if (tid < 11) {
            const float* wp = wsuf + tid * 512 + h * 64;
            for (int d = 0; d < 64; ++d) s += ldin(rpb, h * 64 + d, f32p) * wp[d];
        }
        rpd[tid] = s;
    }
    __syncthreads();
    for (int idx = tid; idx < 32 * 64; idx += 256) {
        int r = idx >> 6, d = idx & 63;
        qc16[(h * NTOK + i0 + r) * DKH + d] = f2b(qs[r][d] + ldin(rcb, h * 64 + d, f32c));
    }
    for (int idx = tid; idx < 32 * 12; idx += 256) {
        int r = idx / 12, t = idx % 12;
        float s = rpd[t];
        if (t < 11) {
            const float* wp = wsuf + t * 512 + h * 64;
            for (int d = 0; d < 64; ++d) s += qs[r][d] * wp[d];
        }
        s11[(h * NTOK + i0 + r) * 12 + t] = s;
    }
}

// ---------------------------------------------------------------------------
// Kernel 3: MFMA flash attention, wave-autonomous.  Grid 768 = 8 heads x 96
// row-tiles; 64 thr = 1 wave = 16 Q-rows x all 1536 keys, split into 2
// independent key-streams (in-register split-K) for ILP.  No staging
// barriers: K/V/Q fragments are direct global bf16 16B loads; P relayout
// (C->A) via per-wave LDS (stride 36 u16: conflict-free writes, 2-way reads).
// ---------------------------------------------------------------------------
__global__ __launch_bounds__(64) void attn_mfma(float* __restrict__ ws) {
    __shared__ float s11buf[16 * 12];
    __shared__ alignas(16) u16 pbuf[2][16 * 36];

    const u16* qc16 = (const u16*)(ws + OFF_QC16);
    const u16* kb16 = (const u16*)(ws + OFF_KB16);
    const u16* vt16 = (const u16*)(ws + OFF_VT16);
    const float* s11 = ws + OFF_S11;
    u16* aob = (u16*)(ws + OFF_AOB);

    int h = blockIdx.x & 7;               // XCD-affine: head h -> XCD h
    int i0 = (blockIdx.x >> 3) * 16;
    int lane = threadIdx.x;
    int quad = lane >> 4, col = lane & 15;

    for (int t = lane; t < 192; t += 64)
        s11buf[t] = s11[(h * NTOK + i0 + t / 12) * 12 + t % 12];

    const u16* qrow = qc16 + (h * NTOK + i0 + col) * DKH;
    s16x8 a_lo = *(const s16x8*)(qrow + quad * 8);
    s16x8 a_hi = *(const s16x8*)(qrow + 32 + quad * 8);
    __syncthreads();

    f32x4 O[2][6];
    float m[2][4], l[2][4];
#pragma unroll
    for (int s = 0; s < 2; ++s) {
#pragma unroll
        for (int nt = 0; nt < 6; ++nt) O[s][nt] = (f32x4){0.f, 0.f, 0.f, 0.f};
#pragma unroll
        for (int r = 0; r < 4; ++r) { m[s][r] = -1e30f; l[s][r] = 0.f; }
    }

    for (int c = 0; c < 24; ++c) {
        f32x4 S[2][2];
        // ---- phase 1: K-frags + QK^T MFMA (both streams) ----
#pragma unroll
        for (int s = 0; s < 2; ++s) {
            int j0 = (s * 24 + c) * 32;
            const u16* k0 = kb16 + (h * NTOK + j0 + col) * DKH;
            const u16* k1 = kb16 + (h * NTOK + j0 + 16 + col) * DKH;
            s16x8 b0lo = *(const s16x8*)(k0 + quad * 8);
            s16x8 b0hi = *(const s16x8*)(k0 + 32 + quad * 8);
            s16x8 b1lo = *(const s16x8*)(k1 + quad * 8);
            s16x8 b1hi = *(const s16x8*)(k1 + 32 + quad * 8);
            f32x4 t0 = (f32x4){0.f, 0.f, 0.f, 0.f};
            f32x4 t1 = (f32x4){0.f, 0.f, 0.f, 0.f};
            t0 = __builtin_amdgcn_mfma_f32_16x16x32_bf16(a_lo, b0lo, t0, 0, 0, 0);
            t0 = __builtin_amdgcn_mfma_f32_16x16x32_bf16(a_hi, b0hi, t0, 0, 0, 0);
            t1 = __builtin_amdgcn_mfma_f32_16x16x32_bf16(a_lo, b1lo, t1, 0, 0, 0);
            t1 = __builtin_amdgcn_mfma_f32_16x16x32_bf16(a_hi, b1hi, t1, 0, 0, 0);
            S[s][0] = t0; S[s][1] = t1;
        }
        // ---- phase 2: +s11, online softmax, P -> LDS (both streams) ----
#pragma unroll
        for (int s = 0; s < 2; ++s) {
            int j0 = (s * 24 + c) * 32;
            float mx[4], rs[4], alpha[4];
#pragma unroll
            for (int r = 0; r < 4; ++r) {
                int row = quad * 4 + r;
                int ig = i0 + row;
                int d0 = ig - (j0 + col); d0 = d0 < 0 ? -d0 : d0;
                int d1 = ig - (j0 + 16 + col); d1 = d1 < 0 ? -d1 : d1;
                float v0 = S[s][0][r] + s11buf[row * 12 + (31 - __builtin_clz(d0 + 1))];
                float v1 = S[s][1][r] + s11buf[row * 12 + (31 - __builtin_clz(d1 + 1))];
                S[s][0][r] = v0; S[s][1][r] = v1;
                mx[r] = fmaxf(v0, v1);
            }
#pragma unroll
            for (int off = 1; off < 16; off <<= 1)
#pragma unroll
                for (int r = 0; r < 4; ++r) mx[r] = fmaxf(mx[r], __shfl_xor(mx[r], off));
#pragma unroll
            for (int r = 0; r < 4; ++r) {
                int row = quad * 4 + r;
                float mn = fmaxf(m[s][r], mx[r]);
                alpha[r] = __expf(m[s][r] - mn);
                m[s][r] = mn;
                float p0 = __expf(S[s][0][r] - mn);
                float p1 = __expf(S[s][1][r] - mn);
                rs[r] = p0 + p1;
                pbuf[s][row * 36 + col] = f2b(p0);
                pbuf[s][row * 36 + 16 + col] = f2b(p1);
            }
#pragma unroll
            for (int off = 1; off < 16; off <<= 1)
#pragma unroll
                for (int r = 0; r < 4; ++r) rs[r] += __shfl_xor(rs[r], off);
#pragma unroll
            for (int r = 0; r < 4; ++r) l[s][r] = l[s][r] * alpha[r] + rs[r];
#pragma unroll
            for (int nt = 0; nt < 6; ++nt)
#pragma unroll
                for (int r = 0; r < 4; ++r) O[s][nt][r] *= alpha[r];
        }
        __syncthreads();  // pbuf cross-lane visibility (1 wave: waitcnt only)
        // ---- phase 3: P A-frag + V B-frags + PV MFMA (both streams) ----
#pragma unroll
        for (int s = 0; s < 2; ++s) {
            int j0 = (s * 24 + c) * 32;
            const u16* pr = &pbuf[s][col * 36 + quad * 8];
            union { s16x8 v; uint2 u2[2]; } pa;
            pa.u2[0] = *(const uint2*)(pr);
            pa.u2[1] = *(const uint2*)(pr + 4);
#pragma unroll
            for (int nt = 0; nt < 6; ++nt) {
                const u16* vr = vt16 + (h * DVH + nt * 16 + col) * NTOK + j0 + quad * 8;
                s16x8 vf = *(const s16x8*)vr;
                O[s][nt] = __builtin_amdgcn_mfma_f32_16x16x32_bf16(pa.v, vf, O[s][nt], 0, 0, 0);
            }
        }
        __syncthreads();  // pbuf reuse guard for next iteration
    }

    // ---- merge streams + epilogue -> bf16 ao ----
#pragma unroll
    for (int r = 0; r < 4; ++r) {
        float mn = fmaxf(m[0][r], m[1][r]);
        float e0 = __expf(m[0][r] - mn);
        float e1 = __expf(m[1][r] - mn);
        float inv = 1.f / (l[0][r] * e0 + l[1][r] * e1);
        int ig = i0 + quad * 4 + r;
#pragma unroll
        for (int nt = 0; nt < 6; ++nt) {
            float val = (O[0][nt][r] * e0 + O[1][nt][r] * e1) * inv;
            aob[ig * CDIM + h * DVH + nt * 16 + col] = f2b(val);
        }
    }
}

// ---------------------------------------------------------------------------
// Kernel 4: output GEMM via bf16 MFMA + bias -> fp32 out.  A = bf16 ao.
// ---------------------------------------------------------------------------
__global__ __launch_bounds__(256) void out_mfma(const void* __restrict__ Wout,
                                                const void* __restrict__ bout,
                                                int fw, int fb,
                                                float* __restrict__ ws,
                                                float* __restrict__ out) {
    __shared__ alignas(16) u16 As[64 * 72];
    __shared__ alignas(16) u16 Bs[64 * 72];
    const int* flags = (const int*)ws;
    const u16* aob = (const u16*)(ws + OFF_AOB);
    int f32w = flags[fw], f32b = flags[fb];

    int tid = threadIdx.x;
    int lane = tid & 63, w = tid >> 6;
    int quad = lane >> 4, col = lane & 15;
    int i0 = blockIdx.x * 64;
    int n0 = blockIdx.y * 64;

    f32x4 acc[4];
#pragma unroll
    for (int mt = 0; mt < 4; ++mt) acc[mt] = (f32x4){0.f, 0.f, 0.f, 0.f};

    for (int k0 = 0; k0 < CDIM; k0 += 64) {
#pragma unroll
        for (int u = 0; u < 4; ++u) {
            int s = tid * 4 + u;
            int row = s >> 4, c4 = (s & 15) * 4;
            *(ushort4*)&As[row * 72 + c4] =
                *(const ushort4*)(aob + (i0 + row) * CDIM + k0 + c4);
        }
#pragma unroll
        for (int u = 0; u < 4; ++u) {
            int s = tid * 4 + u;
            int krow = s >> 4, c4 = (s & 15) * 4;
            u16 b0, b1, b2, b3;
            if (f32w) {
                float4 v = *(const float4*)((const float*)Wout + (k0 + krow) * CDIM + n0 + c4);
                b0 = f2b(v.x); b1 = f2b(v.y); b2 = f2b(v.z); b3 = f2b(v.w);
            } else {
                ushort4 v = *(const ushort4*)((const u16*)Wout + (k0 + krow) * CDIM + n0 + c4);
                b0 = v.x; b1 = v.y; b2 = v.z; b3 = v.w;
            }
            Bs[(c4 + 0) * 72 + krow] = b0;
            Bs[(c4 + 1) * 72 + krow] = b1;
            Bs[(c4 + 2) * 72 + krow] = b2;
            Bs[(c4 + 3) * 72 + krow] = b3;
        }
        __syncthreads();
#pragma unroll
        for (int kc = 0; kc < 2; ++kc) {
            s16x8 bfrag = *(const s16x8*)&Bs[(w * 16 + col) * 72 + kc * 32 + quad * 8];
#pragma unroll
            for (int mt = 0; mt < 4; ++mt) {
                s16x8 afrag = *(const s16x8*)&As[(mt * 16 + col) * 72 + kc * 32 + quad * 8];
                acc[mt] = __builtin_amdgcn_mfma_f32_16x16x32_bf16(afrag, bfrag, acc[mt], 0, 0, 0);
            }
        }
        __syncthreads();
    }

    int c = n0 + w * 16 + col;
    float bias = ldin(bout, c, f32b);
#pragma unroll
    for (int mt = 0; mt < 4; ++mt) {
#pragma unroll
        for (int r = 0; r < 4; ++r) {
            int i = i0 + mt * 16 + quad * 4 + r;
            out[i * CDIM + c] = acc[mt][r] + bias;
        }
    }
}

// ---------------------------------------------------------------------------
extern "C" void kernel_launch(void* const* d_in, const int* in_sizes, int n_in,
                              void* d_out, int out_size, void* d_ws, size_t ws_size,
                              hipStream_t stream) {
    float* out = (float*)d_out;
    float* ws = (float*)d_ws;

    const int want[9] = {1179648, 393216, 393216, 589824, 589824, 768, 49152, 512, 512};
    int role2in[9], used[9] = {0};
    bool ok = (n_in == 9);
    if (ok) {
        for (int r = 0; r < 9; ++r) {
            int found = -1;
            for (int i = 0; i < 9 && found < 0; ++i)
                if (!used[i] && in_sizes[i] == want[r]) found = i;
            if (found < 0) { ok = false; break; }
            used[found] = 1;
            role2in[r] = found;
        }
    }
    if (!ok) for (int r = 0; r < 9; ++r) role2in[r] = r;

    const void* x    = d_in[role2in[0]];
    const void* Wq   = d_in[role2in[1]];
    const void* Wk   = d_in[role2in[2]];
    const void* Wv   = d_in[role2in[3]];
    const void* Wout = d_in[role2in[4]];
    const void* bout = d_in[role2in[5]];
    const void* Wpos = d_in[role2in[6]];
    const void* rcb  = d_in[role2in[7]];
    const void* rpb  = d_in[role2in[8]];

    In9 s;
    for (int i = 0; i < 9; ++i) { s.p[i] = d_in[i]; s.n[i] = in_sizes[i]; }
    hipLaunchKernelGGL(probe_all, dim3(9), dim3(256), 0, stream, s, (int*)ws);

    hipLaunchKernelGGL(wsuf_k, dim3(11), dim3(512), 0, stream, Wpos, role2in[6], ws);
    hipLaunchKernelGGL(qkv_mfma, dim3(24, 28), dim3(256), 0, stream,
                       x, Wq, Wk, Wv, role2in[0], role2in[1], role2in[2], role2in[3], ws);
    hipLaunchKernelGGL(s11_kernel, dim3(384), dim3(256), 0, stream,
                       role2in[8], role2in[7], ws, rpb, rcb);
    hipLaunchKernelGGL(attn_mfma, dim3(768), dim3(64), 0, stream, ws);
    hipLaunchKernelGGL(out_mfma, dim3(24, 12), dim3(256), 0, stream,
                       Wout, bout, role2in[4], role2in[5], ws, out);
}

// Round 9
// 224.976 us; speedup vs baseline: 11.1347x; 1.0590x over previous
//
#include <hip/hip_runtime.h>
#include <stdint.h>

#define NTOK 1536
#define CDIM 768
#define NH 8
#define DKH 64
#define DVH 96
#define NF 96

typedef unsigned short u16;
typedef __attribute__((ext_vector_type(8))) short s16x8;   // 8 bf16 (4 VGPRs)
typedef __attribute__((ext_vector_type(4))) float f32x4;   // MFMA acc

__device__ __forceinline__ float b2f(u16 u) {
    union { uint32_t i; float f; } v; v.i = ((uint32_t)u) << 16; return v.f;
}
__device__ __forceinline__ u16 f2b(float f) {
    union { float f; uint32_t i; } v; v.f = f;
    uint32_t x = v.i;
    return (u16)((x + 0x7FFFu + ((x >> 16) & 1u)) >> 16);
}
__device__ __forceinline__ float ldin(const void* p, int i, int f32) {
    return f32 ? ((const float*)p)[i] : b2f(((const u16*)p)[i]);
}

// ---------------------------------------------------------------------------
// ws layout (float offsets). flags[0..8] at ws[0..8]. ~8.5 MB total.
// ---------------------------------------------------------------------------
#define OFF_WSUF 16
#define OFF_S11  (OFF_WSUF + 5632)
#define OFF_QC16 (OFF_S11 + 147456)    // u16[786432]: bf16 (q*0.125 + rcb), (h,i,d)
#define OFF_KB16 (OFF_QC16 + 393216)   // u16[786432]: bf16 k, (h,j,d)
#define OFF_VT16 (OFF_KB16 + 393216)   // u16[1179648]: bf16 v transposed, (h,d,j)
#define OFF_AOB  (OFF_VT16 + 589824)   // u16[1179648]: bf16 attention out, (i, h*96+d)

struct In9 { const void* p[9]; int n[9]; };

// ---------------------------------------------------------------------------
// Kernel P: per-input dtype probe (2048-elem scan). flags[k]=1 iff fp32.
// ---------------------------------------------------------------------------
__global__ __launch_bounds__(256) void probe_all(In9 s, int* __restrict__ flags) {
    __shared__ int bad;
    int k = blockIdx.x;
    if (threadIdx.x == 0) bad = 0;
    __syncthreads();
    const u16* a = (const u16*)s.p[k];
    int n = s.n[k];
    if (n > 2048) n = 2048;
    int my = 0;
    for (int i = threadIdx.x; i < n; i += 256) {
        float v = b2f(a[i]);
        if (!(fabsf(v) < 1e6f)) my = 1;
    }
    if (my) atomicOr(&bad, 1);
    __syncthreads();
    if (threadIdx.x == 0) flags[k] = bad;
}

// ---------------------------------------------------------------------------
// Kernel 0: wsuf[t][hd] = sum_{f>=t} Wpos[f][hd], t<11.  Parallel: block=t.
// ---------------------------------------------------------------------------
__global__ __launch_bounds__(512) void wsuf_k(const void* __restrict__ Wpos,
                                              int fi, float* __restrict__ ws) {
    int f32 = ((const int*)ws)[fi];
    int hd = threadIdx.x;
    int t = blockIdx.x;  // 0..10
    float s = 0.f;
    for (int f = t; f < NF; ++f) s += ldin(Wpos, f * 512 + hd, f32);
    ws[OFF_WSUF + t * 512 + hd] = s;
}

// ---------------------------------------------------------------------------
// Kernel 1: QKV GEMM via bf16 MFMA 16x16x32, with s11+qc16 FUSED into the
// q-column blocks (a 64-wide n-tile with n0<512 covers exactly one head's
// full 64 q-dims; the staging LDS is reused as an fp32 q-tile after the
// K-loop's final barrier).  k -> bf16 (h,j,d); v -> bf16 transposed (h,d,j).
// ---------------------------------------------------------------------------
__global__ __launch_bounds__(256) void qkv_mfma(const void* __restrict__ x,
                                                const void* __restrict__ Wq,
                                                const void* __restrict__ Wk,
                                                const void* __restrict__ Wv,
                                                const void* __restrict__ rcb,
                                                const void* __restrict__ rpb,
                                                int fx, int fq, int fk, int fv,
                                                int fc, int fp,
                                                float* __restrict__ ws) {
    __shared__ alignas(16) u16 stage[2 * 64 * 72];  // As|Bs; reused as fp32 qt[64*68]
    __shared__ float rpd[12];
    u16* As = stage;
    u16* Bs = stage + 64 * 72;
    float* qt = (float*)stage;

    const int* flags = (const int*)ws;
    u16* qc16 = (u16*)(ws + OFF_QC16);
    u16* kb16 = (u16*)(ws + OFF_KB16);
    u16* vt16 = (u16*)(ws + OFF_VT16);

    int tid = threadIdx.x;
    int lane = tid & 63, w = tid >> 6;
    int quad = lane >> 4, col = lane & 15;
    int i0 = blockIdx.x * 64;
    int n0 = blockIdx.y * 64;

    const void* Bmat; int ldb, col0, fB;
    if (n0 < 512)       { Bmat = Wq; ldb = 512;  col0 = n0;        fB = flags[fq]; }
    else if (n0 < 1024) { Bmat = Wk; ldb = 512;  col0 = n0 - 512;  fB = flags[fk]; }
    else                { Bmat = Wv; ldb = CDIM; col0 = n0 - 1024; fB = flags[fv]; }
    int f32x = flags[fx];
    bool isQ = (n0 < 512);
    int hq = n0 >> 6;  // head for q-blocks

    if (isQ && tid < 12) {  // rpd[t] = rpb[h].wsuf[t]; visible after 1st barrier
        float s = 0.f;
        if (tid < 11) {
            const float* wp = ws + OFF_WSUF + tid * 512 + hq * 64;
            int f32p = flags[fp];
            for (int d = 0; d < 64; ++d) s += ldin(rpb, hq * 64 + d, f32p) * wp[d];
        }
        rpd[tid] = s;
    }

    f32x4 acc[4];
#pragma unroll
    for (int mt = 0; mt < 4; ++mt) acc[mt] = (f32x4){0.f, 0.f, 0.f, 0.f};

    for (int k0 = 0; k0 < CDIM; k0 += 64) {
#pragma unroll
        for (int u = 0; u < 4; ++u) {
            int s = tid * 4 + u;
            int row = s >> 4, c4 = (s & 15) * 4;
            ushort4 o;
            if (f32x) {
                float4 v = *(const float4*)((const float*)x + (i0 + row) * CDIM + k0 + c4);
                o.x = f2b(v.x); o.y = f2b(v.y); o.z = f2b(v.z); o.w = f2b(v.w);
            } else {
                o = *(const ushort4*)((const u16*)x + (i0 + row) * CDIM + k0 + c4);
            }
            *(ushort4*)&As[row * 72 + c4] = o;
        }
#pragma unroll
        for (int u = 0; u < 4; ++u) {
            int s = tid * 4 + u;
            int krow = s >> 4, c4 = (s & 15) * 4;
            u16 b0, b1, b2, b3;
            if (fB) {
                float4 v = *(const float4*)((const float*)Bmat + (k0 + krow) * ldb + col0 + c4);
                b0 = f2b(v.x); b1 = f2b(v.y); b2 = f2b(v.z); b3 = f2b(v.w);
            } else {
                ushort4 v = *(const ushort4*)((const u16*)Bmat + (k0 + krow) * ldb + col0 + c4);
                b0 = v.x; b1 = v.y; b2 = v.z; b3 = v.w;
            }
            Bs[(c4 + 0) * 72 + krow] = b0;
            Bs[(c4 + 1) * 72 + krow] = b1;
            Bs[(c4 + 2) * 72 + krow] = b2;
            Bs[(c4 + 3) * 72 + krow] = b3;
        }
        __syncthreads();
#pragma unroll
        for (int kc = 0; kc < 2; ++kc) {
            s16x8 bfrag = *(const s16x8*)&Bs[(w * 16 + col) * 72 + kc * 32 + quad * 8];
#pragma unroll
            for (int mt = 0; mt < 4; ++mt) {
                s16x8 afrag = *(const s16x8*)&As[(mt * 16 + col) * 72 + kc * 32 + quad * 8];
                acc[mt] = __builtin_amdgcn_mfma_f32_16x16x32_bf16(afrag, bfrag, acc[mt], 0, 0, 0);
            }
        }
        __syncthreads();
    }

    if (isQ) {
        // scaled q -> LDS (stage is free after the loop's final barrier)
#pragma unroll
        for (int mt = 0; mt < 4; ++mt)
#pragma unroll
            for (int r = 0; r < 4; ++r)
                qt[(mt * 16 + quad * 4 + r) * 68 + w * 16 + col] = acc[mt][r] * 0.125f;
        __syncthreads();
        int f32c = flags[fc];
        for (int idx = tid; idx < 64 * 64; idx += 256) {
            int row = idx >> 6, d = idx & 63;
            qc16[(hq * NTOK + i0 + row) * DKH + d] =
                f2b(qt[row * 68 + d] + ldin(rcb, hq * 64 + d, f32c));
        }
        const float* wsuf = ws + OFF_WSUF;
        float* s11 = ws + OFF_S11;
        for (int idx = tid; idx < 64 * 12; idx += 256) {
            int row = idx / 12, t = idx % 12;
            float s = rpd[t];
            if (t < 11) {
                const float* wp = wsuf + t * 512 + hq * 64;
                const float* qr = qt + row * 68;
                for (int d = 0; d < 64; ++d) s += qr[d] * wp[d];
            }
            s11[(hq * NTOK + i0 + row) * 12 + t] = s;
        }
    } else {
        int c = n0 + w * 16 + col;
#pragma unroll
        for (int mt = 0; mt < 4; ++mt) {
#pragma unroll
            for (int r = 0; r < 4; ++r) {
                int i = i0 + mt * 16 + quad * 4 + r;
                float val = acc[mt][r];
                if (c < 1024) {
                    int cc = c - 512;
                    int h = cc >> 6, d = cc & 63;
                    kb16[(h * NTOK + i) * DKH + d] = f2b(val);
                } else {
                    int cc = c - 1024;
                    int h = cc / 96, d = cc % 96;
                    vt16[(h * DVH + d) * NTOK + i] = f2b(val);
                }
            }
        }
    }
}

// ---------------------------------------------------------------------------
// Kernel 3: MFMA flash attention, 4-wave split-K.  Grid 768 = 8 heads x 96
// row-tiles; block = 256 thr = 4 waves.  Wave w handles keys [384w, 384w+384)
// as 2 streams x 6 iters x 32 keys (R8's validated per-wave pipeline).
// Cross-wave online-softmax merge via LDS at the end.
// ---------------------------------------------------------------------------
__global__ __launch_bounds__(256) void attn_mfma(float* __restrict__ ws) {
    __shared__ float s11buf[16 * 12];
    __shared__ alignas(16) u16 pbuf[4][2][16 * 36];
    __shared__ float Om[4][16 * 96];
    __shared__ float mw[4][16], lw[4][16];

    const u16* qc16 = (const u16*)(ws + OFF_QC16);
    const u16* kb16 = (const u16*)(ws + OFF_KB16);
    const u16* vt16 = (const u16*)(ws + OFF_VT16);
    const float* s11 = ws + OFF_S11;
    u16* aob = (u16*)(ws + OFF_AOB);

    int h = blockIdx.x & 7;               // XCD-affine: head h -> XCD h
    int i0 = (blockIdx.x >> 3) * 16;
    int tid = threadIdx.x;
    int wv = tid >> 6, lane = tid & 63;
    int quad = lane >> 4, col = lane & 15;

    if (tid < 192) s11buf[tid] = s11[(h * NTOK + i0 + tid / 12) * 12 + tid % 12];

    const u16* qrow = qc16 + (h * NTOK + i0 + col) * DKH;
    s16x8 a_lo = *(const s16x8*)(qrow + quad * 8);
    s16x8 a_hi = *(const s16x8*)(qrow + 32 + quad * 8);
    __syncthreads();

    f32x4 O[2][6];
    float m[2][4], l[2][4];
#pragma unroll
    for (int s = 0; s < 2; ++s) {
#pragma unroll
        for (int nt = 0; nt < 6; ++nt) O[s][nt] = (f32x4){0.f, 0.f, 0.f, 0.f};
#pragma unroll
        for (int r = 0; r < 4; ++r) { m[s][r] = -1e30f; l[s][r] = 0.f; }
    }

    for (int c = 0; c < 6; ++c) {
        f32x4 S[2][2];
        // ---- phase 1: K-frags + QK^T MFMA ----
#pragma unroll
        for (int s = 0; s < 2; ++s) {
            int j0 = wv * 384 + s * 192 + c * 32;
            const u16* k0 = kb16 + (h * NTOK + j0 + col) * DKH;
            const u16* k1 = kb16 + (h * NTOK + j0 + 16 + col) * DKH;
            s16x8 b0lo = *(const s16x8*)(k0 + quad * 8);
            s16x8 b0hi = *(const s16x8*)(k0 + 32 + quad * 8);
            s16x8 b1lo = *(const s16x8*)(k1 + quad * 8);
            s16x8 b1hi = *(const s16x8*)(k1 + 32 + quad * 8);
            f32x4 t0 = (f32x4){0.f, 0.f, 0.f, 0.f};
            f32x4 t1 = (f32x4){0.f, 0.f, 0.f, 0.f};
            t0 = __builtin_amdgcn_mfma_f32_16x16x32_bf16(a_lo, b0lo, t0, 0, 0, 0);
            t0 = __builtin_amdgcn_mfma_f32_16x16x32_bf16(a_hi, b0hi, t0, 0, 0, 0);
            t1 = __builtin_amdgcn_mfma_f32_16x16x32_bf16(a_lo, b1lo, t1, 0, 0, 0);
            t1 = __builtin_amdgcn_mfma_f32_16x16x32_bf16(a_hi, b1hi, t1, 0, 0, 0);
            S[s][0] = t0; S[s][1] = t1;
        }
        // ---- phase 2: +s11, online softmax, P -> LDS ----
#pragma unroll
        for (int s = 0; s < 2; ++s) {
            int j0 = wv * 384 + s * 192 + c * 32;
            float mx[4], rs[4], alpha[4];
#pragma unroll
            for (int r = 0; r < 4; ++r) {
                int row = quad * 4 + r;
                int ig = i0 + row;
                int d0 = ig - (j0 + col); d0 = d0 < 0 ? -d0 : d0;
                int d1 = ig - (j0 + 16 + col); d1 = d1 < 0 ? -d1 : d1;
                float v0 = S[s][0][r] + s11buf[row * 12 + (31 - __builtin_clz(d0 + 1))];
                float v1 = S[s][1][r] + s11buf[row * 12 + (31 - __builtin_clz(d1 + 1))];
                S[s][0][r] = v0; S[s][1][r] = v1;
                mx[r] = fmaxf(v0, v1);
            }
#pragma unroll
            for (int off = 1; off < 16; off <<= 1)
#pragma unroll
                for (int r = 0; r < 4; ++r) mx[r] = fmaxf(mx[r], __shfl_xor(mx[r], off));
#pragma unroll
            for (int r = 0; r < 4; ++r) {
                int row = quad * 4 + r;
                float mn = fmaxf(m[s][r], mx[r]);
                alpha[r] = __expf(m[s][r] - mn);
                m[s][r] = mn;
                float p0 = __expf(S[s][0][r] - mn);
                float p1 = __expf(S[s][1][r] - mn);
                rs[r] = p0 + p1;
                pbuf[wv][s][row * 36 + col] = f2b(p0);
                pbuf[wv][s][row * 36 + 16 + col] = f2b(p1);
            }
#pragma unroll
            for (int off = 1; off < 16; off <<= 1)
#pragma unroll
                for (int r = 0; r < 4; ++r) rs[r] += __shfl_xor(rs[r], off);
#pragma unroll
            for (int r = 0; r < 4; ++r) l[s][r] = l[s][r] * alpha[r] + rs[r];
#pragma unroll
            for (int nt = 0; nt < 6; ++nt)
#pragma unroll
                for (int r = 0; r < 4; ++r) O[s][nt][r] *= alpha[r];
        }
        __syncthreads();  // pbuf visibility (all 4 waves same trip count)
        // ---- phase 3: P A-frag + V B-frags + PV MFMA ----
#pragma unroll
        for (int s = 0; s < 2; ++s) {
            int j0 = wv * 384 + s * 192 + c * 32;
            const u16* pr = &pbuf[wv][s][col * 36 + quad * 8];
            union { s16x8 v; uint2 u2[2]; } pa;
            pa.u2[0] = *(const uint2*)(pr);
            pa.u2[1] = *(const uint2*)(pr + 4);
#pragma unroll
            for (int nt = 0; nt < 6; ++nt) {
                const u16* vr = vt16 + (h * DVH + nt * 16 + col) * NTOK + j0 + quad * 8;
                s16x8 vf = *(const s16x8*)vr;
                O[s][nt] = __builtin_amdgcn_mfma_f32_16x16x32_bf16(pa.v, vf, O[s][nt], 0, 0, 0);
            }
        }
        __syncthreads();  // pbuf reuse guard
    }

    // ---- intra-wave stream merge (unnormalized) -> LDS ----
#pragma unroll
    for (int r = 0; r < 4; ++r) {
        float mn = fmaxf(m[0][r], m[1][r]);
        float e0 = __expf(m[0][r] - mn);
        float e1 = __expf(m[1][r] - mn);
        int row = quad * 4 + r;
        if (col == 0) { mw[wv][row] = mn; lw[wv][row] = l[0][r] * e0 + l[1][r] * e1; }
#pragma unroll
        for (int nt = 0; nt < 6; ++nt)
            Om[wv][row * 96 + nt * 16 + col] = O[0][nt][r] * e0 + O[1][nt][r] * e1;
    }
    __syncthreads();
    // ---- cross-wave merge + epilogue -> bf16 ao ----
    for (int idx = tid; idx < 16 * 96; idx += 256) {
        int row = idx / 96, cc = idx % 96;
        float m0 = mw[0][row], m1 = mw[1][row], m2 = mw[2][row], m3 = mw[3][row];
        float ms = fmaxf(fmaxf(m0, m1), fmaxf(m2, m3));
        float e0 = __expf(m0 - ms), e1 = __expf(m1 - ms);
        float e2 = __expf(m2 - ms), e3 = __expf(m3 - ms);
        float L = e0 * lw[0][row] + e1 * lw[1][row] + e2 * lw[2][row] + e3 * lw[3][row];
        float val = e0 * Om[0][idx] + e1 * Om[1][idx] + e2 * Om[2][idx] + e3 * Om[3][idx];
        aob[(i0 + row) * CDIM + h * DVH + cc] = f2b(val / L);
    }
}

// ---------------------------------------------------------------------------
// Kernel 4: output GEMM via bf16 MFMA + bias -> fp32 out.  A = bf16 ao.
// ---------------------------------------------------------------------------
__global__ __launch_bounds__(256) void out_mfma(const void* __restrict__ Wout,
                                                const void* __restrict__ bout,
                                                int fw, int fb,
                                                float* __restrict__ ws,
                                                float* __restrict__ out) {
    __shared__ alignas(16) u16 As[64 * 72];
    __shared__ alignas(16) u16 Bs[64 * 72];
    const int* flags = (const int*)ws;
    const u16* aob = (const u16*)(ws + OFF_AOB);
    int f32w = flags[fw], f32b = flags[fb];

    int tid = threadIdx.x;
    int lane = tid & 63, w = tid >> 6;
    int quad = lane >> 4, col = lane & 15;
    int i0 = blockIdx.x * 64;
    int n0 = blockIdx.y * 64;

    f32x4 acc[4];
#pragma unroll
    for (int mt = 0; mt < 4; ++mt) acc[mt] = (f32x4){0.f, 0.f, 0.f, 0.f};

    for (int k0 = 0; k0 < CDIM; k0 += 64) {
#pragma unroll
        for (int u = 0; u < 4; ++u) {
            int s = tid * 4 + u;
            int row = s >> 4, c4 = (s & 15) * 4;
            *(ushort4*)&As[row * 72 + c4] =
                *(const ushort4*)(aob + (i0 + row) * CDIM + k0 + c4);
        }
#pragma unroll
        for (int u = 0; u < 4; ++u) {
            int s = tid * 4 + u;
            int krow = s >> 4, c4 = (s & 15) * 4;
            u16 b0, b1, b2, b3;
            if (f32w) {
                float4 v = *(const float4*)((const float*)Wout + (k0 + krow) * CDIM + n0 + c4);
                b0 = f2b(v.x); b1 = f2b(v.y); b2 = f2b(v.z); b3 = f2b(v.w);
            } else {
                ushort4 v = *(const ushort4*)((const u16*)Wout + (k0 + krow) * CDIM + n0 + c4);
                b0 = v.x; b1 = v.y; b2 = v.z; b3 = v.w;
            }
            Bs[(c4 + 0) * 72 + krow] = b0;
            Bs[(c4 + 1) * 72 + krow] = b1;
            Bs[(c4 + 2) * 72 + krow] = b2;
            Bs[(c4 + 3) * 72 + krow] = b3;
        }
        __syncthreads();
#pragma unroll
        for (int kc = 0; kc < 2; ++kc) {
            s16x8 bfrag = *(const s16x8*)&Bs[(w * 16 + col) * 72 + kc * 32 + quad * 8];
#pragma unroll
            for (int mt = 0; mt < 4; ++mt) {
                s16x8 afrag = *(const s16x8*)&As[(mt * 16 + col) * 72 + kc * 32 + quad * 8];
                acc[mt] = __builtin_amdgcn_mfma_f32_16x16x32_bf16(afrag, bfrag, acc[mt], 0, 0, 0);
            }
        }
        __syncthreads();
    }

    int c = n0 + w * 16 + col;
    float bias = ldin(bout, c, f32b);
#pragma unroll
    for (int mt = 0; mt < 4; ++mt) {
#pragma unroll
        for (int r = 0; r < 4; ++r) {
            int i = i0 + mt * 16 + quad * 4 + r;
            out[i * CDIM + c] = acc[mt][r] + bias;
        }
    }
}

// ---------------------------------------------------------------------------
extern "C" void kernel_launch(void* const* d_in, const int* in_sizes, int n_in,
                              void* d_out, int out_size, void* d_ws, size_t ws_size,
                              hipStream_t stream) {
    float* out = (float*)d_out;
    float* ws = (float*)d_ws;

    const int want[9] = {1179648, 393216, 393216, 589824, 589824, 768, 49152, 512, 512};
    int role2in[9], used[9] = {0};
    bool ok = (n_in == 9);
    if (ok) {
        for (int r = 0; r < 9; ++r) {
            int found = -1;
            for (int i = 0; i < 9 && found < 0; ++i)
                if (!used[i] && in_sizes[i] == want[r]) found = i;
            if (found < 0) { ok = false; break; }
            used[found] = 1;
            role2in[r] = found;
        }
    }
    if (!ok) for (int r = 0; r < 9; ++r) role2in[r] = r;

    const void* x    = d_in[role2in[0]];
    const void* Wq   = d_in[role2in[1]];
    const void* Wk   = d_in[role2in[2]];
    const void* Wv   = d_in[role2in[3]];
    const void* Wout = d_in[role2in[4]];
    const void* bout = d_in[role2in[5]];
    const void* Wpos = d_in[role2in[6]];
    const void* rcb  = d_in[role2in[7]];
    const void* rpb  = d_in[role2in[8]];

    In9 s;
    for (int i = 0; i < 9; ++i) { s.p[i] = d_in[i]; s.n[i] = in_sizes[i]; }
    hipLaunchKernelGGL(probe_all, dim3(9), dim3(256), 0, stream, s, (int*)ws);

    hipLaunchKernelGGL(wsuf_k, dim3(11), dim3(512), 0, stream, Wpos, role2in[6], ws);
    hipLaunchKernelGGL(qkv_mfma, dim3(24, 28), dim3(256), 0, stream,
                       x, Wq, Wk, Wv, rcb, rpb,
                       role2in[0], role2in[1], role2in[2], role2in[3],
                       role2in[7], role2in[8], ws);
    hipLaunchKernelGGL(attn_mfma, dim3(768), dim3(256), 0, stream, ws);
    hipLaunchKernelGGL(out_mfma, dim3(24, 12), dim3(256), 0, stream,
                       Wout, bout, role2in[4], role2in[5], ws, out);
}